// Round 10
// baseline (1795.218 us; speedup 1.0000x reference)
//
#include <hip/hip_runtime.h>
#include <hip/hip_bf16.h>
#include <cstddef>

#define BB 64
#define TXX 128
#define TYY 48
#define NSS 47
#define EE 512
#define HH 1024
#define VV 32000

typedef _Float16 f16x8 __attribute__((ext_vector_type(8)));
typedef float f32x4 __attribute__((ext_vector_type(4)));
typedef unsigned short ush;
typedef ush ushx4 __attribute__((ext_vector_type(4)));

__device__ __forceinline__ ush f2h(float x) {
    _Float16 h = (_Float16)x;
    return __builtin_bit_cast(ush, h);
}
__device__ __forceinline__ float h2f(ush u) {
    return (float)__builtin_bit_cast(_Float16, u);
}
// cached global->LDS DMA (proven rounds 1-9)
__device__ __forceinline__ void gload16(const void* g, void* l) {
    __builtin_amdgcn_global_load_lds(
        (const __attribute__((address_space(1))) unsigned int*)g,
        (__attribute__((address_space(3))) unsigned int*)l, 16, 0, 0);
}
__device__ __forceinline__ void st_agent_u32(void* p, unsigned v) {
    __hip_atomic_store((unsigned*)p, v, __ATOMIC_RELAXED, __HIP_MEMORY_SCOPE_AGENT);
}
__device__ __forceinline__ unsigned ld_agent_u32(const void* p) {
    return __hip_atomic_load((const unsigned*)p, __ATOMIC_RELAXED, __HIP_MEMORY_SCOPE_AGENT);
}
__device__ __forceinline__ float sigm(float x) { return 1.f / (1.f + expf(-x)); }

// Flag-array row-group barrier: block j stores step to its OWN flag (no RMW
// contention); wave 0's lanes poll the 64 contiguous flags (coalesced).
// Monotonic step values => same skew<=1 protocol proven in rounds 8-9.
__device__ __forceinline__ void gbar(unsigned* flags, int j, unsigned step) {
    asm volatile("s_waitcnt vmcnt(0)" ::: "memory");
    __syncthreads();
    if (threadIdx.x < 64) {
        if (threadIdx.x == 0) st_agent_u32(flags + j, step);
        while (ld_agent_u32(flags + threadIdx.x) < step)
            __builtin_amdgcn_s_sleep(1);
    }
    __syncthreads();
}

// ---------------------------------------------------------------------------
// Transpose + f32->f16 (unchanged)
// ---------------------------------------------------------------------------
__global__ __launch_bounds__(256) void transpose_w(
    const float* __restrict__ W, ush* __restrict__ Wt, int ldW, int ldT)
{
    __shared__ float t[32][33];
    int v0 = blockIdx.x * 32, k0 = blockIdx.y * 32;
    int tv = threadIdx.x & 31, tk = threadIdx.x >> 5;
    #pragma unroll
    for (int i = 0; i < 4; i++) {
        int k = tk * 4 + i;
        t[k][tv] = W[(size_t)(k0 + k) * ldW + v0 + tv];
    }
    __syncthreads();
    #pragma unroll
    for (int i = 0; i < 4; i++) {
        int v = tk * 4 + i;
        Wt[(size_t)(v0 + v) * ldT + k0 + tv] = f2h(t[tv][v]);
    }
}

// ---------------------------------------------------------------------------
// Embedding gather + f16 convert (unchanged)
// ---------------------------------------------------------------------------
__global__ __launch_bounds__(256) void gather_emb(
    const float* __restrict__ emb, const int* __restrict__ tok,
    ush* __restrict__ out, int tokld, int tmax)
{
    int i = blockIdx.x * 256 + threadIdx.x;
    int r = i >> 6, kq = (i & 63) * 8;
    int t = r >> 6, b = r & 63;
    ush v[8];
    if (t < tmax) {
        int tk = tok[b * tokld + t];
        const float* e = emb + (size_t)tk * EE + kq;
        #pragma unroll
        for (int j = 0; j < 8; j++) v[j] = f2h(e[j]);
    } else {
        #pragma unroll
        for (int j = 0; j < 8; j++) v[j] = 0;
    }
    *reinterpret_cast<f16x8*>(&out[(size_t)r * EE + kq]) =
        *reinterpret_cast<f16x8*>(v);
}

// ---------------------------------------------------------------------------
// f16 MFMA GEMM, 128x128 tile + XCD-aware block swizzle (T1; requires
// gridDim.x*gridDim.y % 8 == 0 — true for all call sites). MODE:
//  0: f32 C row-major + bias; 1: out-proj permute + bias; 2: f16 C;
//  3: f16 C, tanh(acc+bias). Guards row<Mvalid (MODE 1: row<3008).
// ---------------------------------------------------------------------------
template <int MODE>
__global__ __launch_bounds__(256) void gemm_f16(
    const ush* __restrict__ A, int lda, const ush* __restrict__ Bt,
    const float* __restrict__ bias, void* __restrict__ Cv,
    int K, int Nld, int Mvalid)
{
    __shared__ ush As[128 * 64];
    __shared__ ush Bs[128 * 64];
    const int tid = threadIdx.x;
    const int lane = tid & 63;
    const int w = tid >> 6;
    const int wm = w >> 1, wn = w & 1;
    // XCD swizzle: XCD k (orig%8==k) gets a contiguous swz chunk =>
    // consecutive M-tiles of one N-panel share the Bt panel in that L2.
    const int nwg = gridDim.x * gridDim.y;
    const int orig = blockIdx.y * gridDim.x + blockIdx.x;
    const int swz = (orig & 7) * (nwg >> 3) + (orig >> 3);
    const int m0 = (swz % gridDim.x) * 128;
    const int n0 = (swz / gridDim.x) * 128;

    f32x4 acc[4][4] = {};
    const int srow = w * 32 + (lane >> 3);
    const int skoff = (lane & 7) * 8;

    for (int kb = 0; kb < K; kb += 64) {
        #pragma unroll
        for (int c = 0; c < 4; c++) {
            const ush* ga = A + (size_t)(m0 + srow + c * 8) * lda + kb + skoff;
            gload16(ga, &As[(w * 4 + c) * 512]);
        }
        #pragma unroll
        for (int c = 0; c < 4; c++) {
            const ush* gb = Bt + (size_t)(n0 + srow + c * 8) * K + kb + skoff;
            gload16(gb, &Bs[(w * 4 + c) * 512]);
        }
        __syncthreads();

        #pragma unroll
        for (int kw = 0; kw < 2; kw++) {
            const int koff = kw * 32 + (lane >> 4) * 8;
            f16x8 af[4], bf[4];
            #pragma unroll
            for (int m = 0; m < 4; m++)
                af[m] = *(const f16x8*)&As[(wm * 64 + m * 16 + (lane & 15)) * 64 + koff];
            #pragma unroll
            for (int n = 0; n < 4; n++)
                bf[n] = *(const f16x8*)&Bs[(wn * 64 + n * 16 + (lane & 15)) * 64 + koff];
            #pragma unroll
            for (int m = 0; m < 4; m++)
                #pragma unroll
                for (int n = 0; n < 4; n++)
                    acc[m][n] = __builtin_amdgcn_mfma_f32_16x16x32_f16(
                        af[m], bf[n], acc[m][n], 0, 0, 0);
        }
        __syncthreads();
    }

    #pragma unroll
    for (int n = 0; n < 4; n++) {
        int v = n0 + wn * 64 + n * 16 + (lane & 15);
        float bs = (MODE == 2) ? 0.f : (bias ? bias[v] : 0.f);
        #pragma unroll
        for (int m = 0; m < 4; m++) {
            int rbase = m0 + wm * 64 + m * 16 + (lane >> 4) * 4;
            #pragma unroll
            for (int r = 0; r < 4; r++) {
                int row = rbase + r;
                float val = acc[m][n][r] + bs;
                if (MODE == 1) {
                    if (row < 3008) {
                        int b = row & 63, s = row >> 6;
                        ((float*)Cv)[((size_t)b * NSS + s) * VV + v] = val;
                    }
                } else if (MODE == 0) {
                    if (row < Mvalid) ((float*)Cv)[(size_t)row * Nld + v] = val;
                } else if (MODE == 2) {
                    if (row < Mvalid) ((ush*)Cv)[(size_t)row * Nld + v] = f2h(val);
                } else {
                    if (row < Mvalid)
                        ((ush*)Cv)[(size_t)row * Nld + v] = f2h(tanhf(val));
                }
            }
        }
    }
}

// ===========================================================================
// Persistent recurrent kernel (round-9 structure, flag barrier): 256 blocks
// = 4 row-groups (16 batch rows) x 64 col-groups (16 hidden cols x 4 gates).
// Weights LDS-resident (128 KiB); c in registers; h exchanged via agent
// stores to fresh addresses (enc16[t]/Hcat[s]) + plain cached reads.
// ===========================================================================
struct RecArgs {
    const ush *Whe, *Whd, *Gxe, *Gxd;
    const float *ebi, *ebf, *ebo, *ebc;
    const float *dbi, *dbf, *dbo, *dbc;
    ush *enc16, *Hcat;
    unsigned* bar;
};

__device__ __forceinline__ void stageWh(const ush* __restrict__ Wh, int j, int kb,
                                        int w, int lane, ush* Ws)
{
    #pragma unroll
    for (int c8 = 0; c8 < 4; c8++) {
        int s = (c8 * 4 + w) * 64 + lane;
        int r = s >> 4, scc = (s & 15) ^ (r & 7);
        gload16(Wh + ((size_t)((r >> 4) * 1024 + j * 16 + (r & 15))) * 1024 + kb + scc * 8,
                Ws + (size_t)(c8 * 4 + w) * 512);
    }
}

__device__ __forceinline__ void lstm_step2(
    const ush* __restrict__ hsrc, int hstride, ush* __restrict__ hdst, int dstride,
    const ush* __restrict__ gx,
    float Bi, float Bf, float Bo, float Bc, float& creg,
    ush (*Whs)[8192], ush (*AsL)[2048],
    int rg, int j, int tid, unsigned* flags, unsigned step)
{
    const int w = tid >> 6, lane = tid & 63;
    const int r = tid >> 4, sl = tid & 15;      // (local row, slot/cc)
    const int gb = rg * 16 + r;                 // global batch row
    const int gcc = j * 16 + sl;                // global hidden col

    // Gx prefetch (consumed in epilogue; latency hidden under MFMA)
    const ush* gxr = gx + (size_t)gb * 4096 + gcc;
    ush gxi = gxr[0], gxf = gxr[1024], gxo = gxr[2048], gxc = gxr[3072];

    // A-tile stage: [16 rows][1024] as 8 chunks [16][128], slot-XOR swizzle.
    if (hsrc) {
        uint4 ra[8];
        const ush* rowp = hsrc + (size_t)gb * hstride;
        #pragma unroll
        for (int ch = 0; ch < 8; ch++)
            ra[ch] = *reinterpret_cast<const uint4*>(rowp + ch * 128 + sl * 8);
        #pragma unroll
        for (int ch = 0; ch < 8; ch++)
            *reinterpret_cast<uint4*>(&AsL[ch][r * 128 + (sl ^ (r & 7)) * 8]) = ra[ch];
    } else {
        uint4 z = {0, 0, 0, 0};
        #pragma unroll
        for (int ch = 0; ch < 8; ch++)
            *reinterpret_cast<uint4*>(&AsL[ch][r * 128 + sl * 8]) = z;
    }
    __syncthreads();

    // gate-per-wave MFMA: wave w = gate w, [16 rows]x[16 cc], K=1024
    f32x4 acc = {};
    #pragma unroll
    for (int ch = 0; ch < 8; ch++) {
        #pragma unroll
        for (int kw = 0; kw < 4; kw++) {
            int colo = kw * 32 + (lane >> 4) * 8;
            int ar = lane & 15;
            f16x8 af = *(const f16x8*)&AsL[ch][(ar * 128 + colo) ^ ((ar & 7) << 3)];
            int br = w * 16 + (lane & 15);
            f16x8 bfv = *(const f16x8*)&Whs[ch][(br * 128 + colo) ^ ((br & 7) << 3)];
            acc = __builtin_amdgcn_mfma_f32_16x16x32_f16(af, bfv, acc, 0, 0, 0);
        }
    }
    __syncthreads();                 // all waves done reading AsL
    float* zb = (float*)AsL;         // 4 KB z-exchange aliases A-tile
    #pragma unroll
    for (int rr = 0; rr < 4; rr++)
        zb[(w * 16 + (lane >> 4) * 4 + rr) * 16 + (lane & 15)] = acc[rr];
    __syncthreads();

    // elementwise epilogue: thread owns (gb, gcc); c in register
    float zi = zb[(r) * 16 + sl]      + Bi + h2f(gxi);
    float zf = zb[(16 + r) * 16 + sl] + Bf + h2f(gxf);
    float zo = zb[(32 + r) * 16 + sl] + Bo + h2f(gxo);
    float zc = zb[(48 + r) * 16 + sl] + Bc + h2f(gxc);
    float F = sigm(zf), I = sigm(zi), O = sigm(zo), G = tanhf(zc);
    creg = F * creg + I * G;
    float hn = O * tanhf(creg);
    unsigned hv = (unsigned)f2h(hn);
    unsigned other = __shfl_xor(hv, 1, 64);   // pair adjacent cc
    if ((lane & 1) == 0)
        st_agent_u32(hdst + (size_t)gb * dstride + gcc, hv | (other << 16));

    gbar(flags, j, step);
}

__global__ __launch_bounds__(256) void recurrent_all(RecArgs a)
{
    __shared__ ush Whs[8][8192];   // 128 KiB resident weight slice
    __shared__ ush AsL[8][2048];   // 32 KiB A-tile (aliased by z-exchange)
    const int bid = blockIdx.x;
    const int rg = bid >> 6;       // row-group 0..3 (contiguous in dispatch)
    const int j = bid & 63;        // col-group: hidden cols j*16..j*16+15
    const int tid = threadIdx.x;
    const int w = tid >> 6, lane = tid & 63;
    const int gcc = j * 16 + (tid & 15);
    unsigned* flags = a.bar + rg * 64;   // 64 flags per row-group (256 B)
    unsigned nb = 0;
    float creg = 0.f;

    // ---- encoder ----
    for (int ch = 0; ch < 8; ch++) stageWh(a.Whe, j, ch * 128, w, lane, Whs[ch]);
    {
        float Bi = a.ebi[gcc], Bf = a.ebf[gcc], Bo = a.ebo[gcc], Bc = a.ebc[gcc];
        for (int t = 0; t < TXX; t++) {
            const ush* hsrc = (t == 0) ? nullptr : a.enc16 + (size_t)(t - 1) * 65536;
            lstm_step2(hsrc, 1024, a.enc16 + (size_t)t * 65536, 1024,
                       a.Gxe + (size_t)t * 262144, Bi, Bf, Bo, Bc, creg,
                       Whs, AsL, rg, j, tid, flags, ++nb);
        }
    }
    // ---- decoder ----
    for (int ch = 0; ch < 8; ch++) stageWh(a.Whd, j, ch * 128, w, lane, Whs[ch]);
    {
        float Bi = a.dbi[gcc], Bf = a.dbf[gcc], Bo = a.dbo[gcc], Bc = a.dbc[gcc];
        for (int s = 0; s < NSS; s++) {
            const ush* hsrc = (s == 0) ? a.enc16 + (size_t)127 * 65536
                                       : a.Hcat + (size_t)(s - 1) * 64 * 2048;
            int hstride = (s == 0) ? 1024 : 2048;
            lstm_step2(hsrc, hstride, a.Hcat + (size_t)s * 64 * 2048, 2048,
                       a.Gxd + (size_t)s * 262144, Bi, Bf, Bo, Bc, creg,
                       Whs, AsL, rg, j, tid, flags, ++nb);
        }
    }
}

// ---------------------------------------------------------------------------
// Batched attention (unchanged): one block per (s, b).
// ---------------------------------------------------------------------------
__global__ __launch_bounds__(256) void attn_batched(
    const float* __restrict__ q, const ush* __restrict__ enc16,
    ush* __restrict__ Hcat)
{
    int s = blockIdx.x, b = blockIdx.y;
    int row = s * 64 + b;
    int tid = threadIdx.x;
    __shared__ float qs[1024];
    __shared__ float sc[130];

    for (int i = tid; i < 1024; i += 256) qs[i] = q[(size_t)row * 1024 + i];
    __syncthreads();

    int wave = tid >> 6, lane = tid & 63;
    for (int i = 0; i < 32; i++) {
        int t = wave * 32 + i;
        const ush* e = enc16 + ((size_t)t * 64 + b) * 1024;
        float sv = 0.f;
        #pragma unroll
        for (int jj = 0; jj < 16; jj++) sv += qs[lane + jj * 64] * h2f(e[lane + jj * 64]);
        #pragma unroll
        for (int o = 32; o > 0; o >>= 1) sv += __shfl_down(sv, o, 64);
        if (lane == 0) sc[t] = sv;
    }
    __syncthreads();

    if (wave == 0) {
        float v = fmaxf(sc[lane], sc[lane + 64]);
        #pragma unroll
        for (int o = 32; o > 0; o >>= 1) v = fmaxf(v, __shfl_down(v, o, 64));
        if (lane == 0) sc[128] = v;
    }
    __syncthreads();
    float mx = sc[128];
    if (wave == 0) {
        float e0 = expf(sc[lane] - mx), e1 = expf(sc[lane + 64] - mx);
        sc[lane] = e0; sc[lane + 64] = e1;
        float v = e0 + e1;
        #pragma unroll
        for (int o = 32; o > 0; o >>= 1) v += __shfl_down(v, o, 64);
        if (lane == 0) sc[129] = v;
    }
    __syncthreads();
    float inv = 1.f / sc[129];

    int h0 = tid * 4;
    float a0 = 0.f, a1 = 0.f, a2 = 0.f, a3 = 0.f;
    #pragma unroll 4
    for (int t = 0; t < 128; t++) {
        float av = sc[t] * inv;
        ushx4 ev = *reinterpret_cast<const ushx4*>(
            enc16 + ((size_t)t * 64 + b) * 1024 + h0);
        a0 += av * h2f(ev[0]); a1 += av * h2f(ev[1]);
        a2 += av * h2f(ev[2]); a3 += av * h2f(ev[3]);
    }
    ushx4 o = {f2h(a0), f2h(a1), f2h(a2), f2h(a3)};
    *reinterpret_cast<ushx4*>(&Hcat[(size_t)row * 2048 + 1024 + h0]) = o;
}

// ---------------------------------------------------------------------------
extern "C" void kernel_launch(void* const* d_in, const int* in_sizes, int n_in,
                              void* d_out, int out_size, void* d_ws, size_t ws_size,
                              hipStream_t stream)
{
    const int*   x       = (const int*)d_in[0];
    const int*   y       = (const int*)d_in[1];
    const float* enc_emb = (const float*)d_in[2];
    const float* dec_emb = (const float*)d_in[3];
    const float* encW[4] = {(const float*)d_in[4], (const float*)d_in[6],
                            (const float*)d_in[8], (const float*)d_in[10]};
    const float* encB[4] = {(const float*)d_in[5], (const float*)d_in[7],
                            (const float*)d_in[9], (const float*)d_in[11]};
    const float* decW[4] = {(const float*)d_in[12], (const float*)d_in[14],
                            (const float*)d_in[16], (const float*)d_in[18]};
    const float* decB[4] = {(const float*)d_in[13], (const float*)d_in[15],
                            (const float*)d_in[17], (const float*)d_in[19]};
    const float* attn_w  = (const float*)d_in[20];
    const float* attn_b  = (const float*)d_in[21];
    const float* lin_w   = (const float*)d_in[22];
    const float* lin_b   = (const float*)d_in[23];
    const float* out_w   = (const float*)d_in[24];
    const float* out_b   = (const float*)d_in[25];

    // ws layout: same proven extents (high-water 30408704 f)
    float* ws = (float*)d_ws;
    ush*   preh   = (ush*)(ws + 393216);         // 3072x1024 ush (3008 valid)
    ush*   enc16  = (ush*)(ws + 1966080);        // 128x64x1024 ush
    ush*   Wt     = (ush*)(ws + 6160384);        // 32000x1024 ush
    ush*   Whe    = (ush*)(ws + 22544384);       // 4096x1024 ush
    ush*   Whd    = (ush*)(ws + 24641536);
    ush*   Wxe    = (ush*)(ws + 26738688);       // 4096x512 ush
    ush*   Wxd    = (ush*)(ws + 27787264);
    ush*   attn_t = (ush*)(ws + 28835840);       // 1024x1024 ush
    ush*   lin_t  = (ush*)(ws + 29360128);       // 1024x2048 ush
    // 4 x 64 barrier flags in preh PAD rows (zeroed each launch; only read
    // back as discarded guarded A-pad) — proven location.
    unsigned* bar = (unsigned*)(preh + (size_t)3008 * 1024);

    // dead-before-outproj scratch in d_out
    ush*   Gx_enc = (ush*)d_out;                     // 8192*4096
    ush*   Gx_dec = Gx_enc + (size_t)8192 * 4096;    // 3072*4096
    ush*   Xe     = Gx_dec + (size_t)3072 * 4096;    // 8192*512
    ush*   Ye     = Xe + (size_t)8192 * 512;         // 3072*512
    ush*   Hcat   = Ye + (size_t)3072 * 512;         // 3072*2048
    float* qbuf   = (float*)(Hcat + (size_t)3072 * 2048);  // 3072*1024 f32

    hipMemsetAsync(preh, 0, (size_t)3072 * 1024 * 2, stream); // pad + flags

    // ---- weight prep ----
    transpose_w<<<dim3(VV / 32, 32), 256, 0, stream>>>(out_w, Wt, VV, HH);
    transpose_w<<<dim3(32, 32), 256, 0, stream>>>(attn_w, attn_t, HH, HH);
    transpose_w<<<dim3(32, 64), 256, 0, stream>>>(lin_w, lin_t, HH, 2048);
    for (int g = 0; g < 4; g++) {
        transpose_w<<<dim3(32, 32), 256, 0, stream>>>(
            encW[g] + (size_t)EE * HH, Whe + (size_t)g * 1024 * 1024, HH, HH);
        transpose_w<<<dim3(32, 32), 256, 0, stream>>>(
            decW[g] + (size_t)EE * HH, Whd + (size_t)g * 1024 * 1024, HH, HH);
        transpose_w<<<dim3(32, 16), 256, 0, stream>>>(
            encW[g], Wxe + (size_t)g * 1024 * 512, HH, EE);
        transpose_w<<<dim3(32, 16), 256, 0, stream>>>(
            decW[g], Wxd + (size_t)g * 1024 * 512, HH, EE);
    }

    // ---- embedding gathers ----
    gather_emb<<<dim3(2048), 256, 0, stream>>>(enc_emb, x, Xe, TXX, TXX);
    gather_emb<<<dim3(768), 256, 0, stream>>>(dec_emb, y, Ye, TYY, NSS);

    // ---- x-side gate precompute ----
    gemm_f16<2><<<dim3(64, 32), 256, 0, stream>>>(
        Xe, EE, Wxe, nullptr, Gx_enc, EE, 4096, 8192);
    gemm_f16<2><<<dim3(24, 32), 256, 0, stream>>>(
        Ye, EE, Wxd, nullptr, Gx_dec, EE, 4096, 3072);

    // ---- persistent recurrent kernel (plain launch; 256 blocks, 1/CU) ----
    RecArgs ra;
    ra.Whe = Whe; ra.Whd = Whd; ra.Gxe = Gx_enc; ra.Gxd = Gx_dec;
    ra.ebi = encB[0]; ra.ebf = encB[1]; ra.ebo = encB[2]; ra.ebc = encB[3];
    ra.dbi = decB[0]; ra.dbf = decB[1]; ra.dbo = decB[2]; ra.dbc = decB[3];
    ra.enc16 = enc16; ra.Hcat = Hcat; ra.bar = bar;
    recurrent_all<<<dim3(256), dim3(256), 0, stream>>>(ra);

    // ---- post-recurrent batched phases ----
    gemm_f16<0><<<dim3(24, 8), 256, 0, stream>>>(
        Hcat, 2048, attn_t, attn_b, qbuf, HH, HH, 3008);
    attn_batched<<<dim3(NSS, 64), 256, 0, stream>>>(qbuf, enc16, Hcat);
    gemm_f16<3><<<dim3(24, 8), 256, 0, stream>>>(
        Hcat, 2048, lin_t, lin_b, preh, 2048, HH, 3008);

    // ---- output projection ----
    gemm_f16<1><<<dim3(24, VV / 128), 256, 0, stream>>>(
        preh, HH, Wt, out_b, d_out, HH, VV, 3008);
}

// Round 11
// 1662.969 us; speedup vs baseline: 1.0795x; 1.0795x over previous
//
#include <hip/hip_runtime.h>
#include <hip/hip_bf16.h>
#include <cstddef>

#define BB 64
#define TXX 128
#define TYY 48
#define NSS 47
#define EE 512
#define HH 1024
#define VV 32000

typedef _Float16 f16x8 __attribute__((ext_vector_type(8)));
typedef float f32x4 __attribute__((ext_vector_type(4)));
typedef unsigned short ush;
typedef ush ushx4 __attribute__((ext_vector_type(4)));

__device__ __forceinline__ ush f2h(float x) {
    _Float16 h = (_Float16)x;
    return __builtin_bit_cast(ush, h);
}
__device__ __forceinline__ float h2f(ush u) {
    return (float)__builtin_bit_cast(_Float16, u);
}
// cached global->LDS DMA (proven rounds 1-10)
__device__ __forceinline__ void gload16(const void* g, void* l) {
    __builtin_amdgcn_global_load_lds(
        (const __attribute__((address_space(1))) unsigned int*)g,
        (__attribute__((address_space(3))) unsigned int*)l, 16, 0, 0);
}
__device__ __forceinline__ void st_agent_u32(void* p, unsigned v) {
    __hip_atomic_store((unsigned*)p, v, __ATOMIC_RELAXED, __HIP_MEMORY_SCOPE_AGENT);
}
__device__ __forceinline__ float sigm(float x) { return 1.f / (1.f + expf(-x)); }

// Round-9 proven relaxed row-group barrier (single counter + fetch_add).
// Round-10's flag-array variant regressed (+1.1us/step) — reverted.
__device__ __forceinline__ void gbar(unsigned* bar, unsigned target) {
    asm volatile("s_waitcnt vmcnt(0)" ::: "memory");
    __syncthreads();
    if (threadIdx.x == 0) {
        __hip_atomic_fetch_add(bar, 1u, __ATOMIC_RELAXED, __HIP_MEMORY_SCOPE_AGENT);
        while (__hip_atomic_load(bar, __ATOMIC_RELAXED, __HIP_MEMORY_SCOPE_AGENT) < target) {
            __builtin_amdgcn_s_sleep(2);
        }
    }
    __syncthreads();
}

// ---------------------------------------------------------------------------
// Transpose + f32->f16 (unchanged)
// ---------------------------------------------------------------------------
__global__ __launch_bounds__(256) void transpose_w(
    const float* __restrict__ W, ush* __restrict__ Wt, int ldW, int ldT)
{
    __shared__ float t[32][33];
    int v0 = blockIdx.x * 32, k0 = blockIdx.y * 32;
    int tv = threadIdx.x & 31, tk = threadIdx.x >> 5;
    #pragma unroll
    for (int i = 0; i < 4; i++) {
        int k = tk * 4 + i;
        t[k][tv] = W[(size_t)(k0 + k) * ldW + v0 + tv];
    }
    __syncthreads();
    #pragma unroll
    for (int i = 0; i < 4; i++) {
        int v = tk * 4 + i;
        Wt[(size_t)(v0 + v) * ldT + k0 + tv] = f2h(t[tv][v]);
    }
}

// ---------------------------------------------------------------------------
// Embedding gather + f16 convert (unchanged)
// ---------------------------------------------------------------------------
__global__ __launch_bounds__(256) void gather_emb(
    const float* __restrict__ emb, const int* __restrict__ tok,
    ush* __restrict__ out, int tokld, int tmax)
{
    int i = blockIdx.x * 256 + threadIdx.x;
    int r = i >> 6, kq = (i & 63) * 8;
    int t = r >> 6, b = r & 63;
    ush v[8];
    if (t < tmax) {
        int tk = tok[b * tokld + t];
        const float* e = emb + (size_t)tk * EE + kq;
        #pragma unroll
        for (int j = 0; j < 8; j++) v[j] = f2h(e[j]);
    } else {
        #pragma unroll
        for (int j = 0; j < 8; j++) v[j] = 0;
    }
    *reinterpret_cast<f16x8*>(&out[(size_t)r * EE + kq]) =
        *reinterpret_cast<f16x8*>(v);
}

// ---------------------------------------------------------------------------
// f16 MFMA GEMM, 128x128 tile + XCD-aware block swizzle (kept; neutral-to-
// positive). Requires nwg % 8 == 0 — true for all call sites. MODE:
//  0: f32 C row-major + bias; 1: out-proj permute + bias; 2: f16 C;
//  3: f16 C, tanh(acc+bias). Guards row<Mvalid (MODE 1: row<3008).
// ---------------------------------------------------------------------------
template <int MODE>
__global__ __launch_bounds__(256) void gemm_f16(
    const ush* __restrict__ A, int lda, const ush* __restrict__ Bt,
    const float* __restrict__ bias, void* __restrict__ Cv,
    int K, int Nld, int Mvalid)
{
    __shared__ ush As[128 * 64];
    __shared__ ush Bs[128 * 64];
    const int tid = threadIdx.x;
    const int lane = tid & 63;
    const int w = tid >> 6;
    const int wm = w >> 1, wn = w & 1;
    const int nwg = gridDim.x * gridDim.y;
    const int orig = blockIdx.y * gridDim.x + blockIdx.x;
    const int swz = (orig & 7) * (nwg >> 3) + (orig >> 3);
    const int m0 = (swz % gridDim.x) * 128;
    const int n0 = (swz / gridDim.x) * 128;

    f32x4 acc[4][4] = {};
    const int srow = w * 32 + (lane >> 3);
    const int skoff = (lane & 7) * 8;

    for (int kb = 0; kb < K; kb += 64) {
        #pragma unroll
        for (int c = 0; c < 4; c++) {
            const ush* ga = A + (size_t)(m0 + srow + c * 8) * lda + kb + skoff;
            gload16(ga, &As[(w * 4 + c) * 512]);
        }
        #pragma unroll
        for (int c = 0; c < 4; c++) {
            const ush* gb = Bt + (size_t)(n0 + srow + c * 8) * K + kb + skoff;
            gload16(gb, &Bs[(w * 4 + c) * 512]);
        }
        __syncthreads();

        #pragma unroll
        for (int kw = 0; kw < 2; kw++) {
            const int koff = kw * 32 + (lane >> 4) * 8;
            f16x8 af[4], bf[4];
            #pragma unroll
            for (int m = 0; m < 4; m++)
                af[m] = *(const f16x8*)&As[(wm * 64 + m * 16 + (lane & 15)) * 64 + koff];
            #pragma unroll
            for (int n = 0; n < 4; n++)
                bf[n] = *(const f16x8*)&Bs[(wn * 64 + n * 16 + (lane & 15)) * 64 + koff];
            #pragma unroll
            for (int m = 0; m < 4; m++)
                #pragma unroll
                for (int n = 0; n < 4; n++)
                    acc[m][n] = __builtin_amdgcn_mfma_f32_16x16x32_f16(
                        af[m], bf[n], acc[m][n], 0, 0, 0);
        }
        __syncthreads();
    }

    #pragma unroll
    for (int n = 0; n < 4; n++) {
        int v = n0 + wn * 64 + n * 16 + (lane & 15);
        float bs = (MODE == 2) ? 0.f : (bias ? bias[v] : 0.f);
        #pragma unroll
        for (int m = 0; m < 4; m++) {
            int rbase = m0 + wm * 64 + m * 16 + (lane >> 4) * 4;
            #pragma unroll
            for (int r = 0; r < 4; r++) {
                int row = rbase + r;
                float val = acc[m][n][r] + bs;
                if (MODE == 1) {
                    if (row < 3008) {
                        int b = row & 63, s = row >> 6;
                        ((float*)Cv)[((size_t)b * NSS + s) * VV + v] = val;
                    }
                } else if (MODE == 0) {
                    if (row < Mvalid) ((float*)Cv)[(size_t)row * Nld + v] = val;
                } else if (MODE == 2) {
                    if (row < Mvalid) ((ush*)Cv)[(size_t)row * Nld + v] = f2h(val);
                } else {
                    if (row < Mvalid)
                        ((ush*)Cv)[(size_t)row * Nld + v] = f2h(tanhf(val));
                }
            }
        }
    }
}

// ===========================================================================
// Persistent recurrent kernel (round-9 structure + round-9 barrier): 256
// blocks = 4 row-groups (16 batch rows) x 64 col-groups (16 cols x 4 gates).
// Weights LDS-resident (128 KiB); c in registers; h exchanged via agent
// stores to fresh addresses (enc16[t]/Hcat[s]) + plain cached reads.
// ===========================================================================
struct RecArgs {
    const ush *Whe, *Whd, *Gxe, *Gxd;
    const float *ebi, *ebf, *ebo, *ebc;
    const float *dbi, *dbf, *dbo, *dbc;
    ush *enc16, *Hcat;
    unsigned* bar;
};

__device__ __forceinline__ void stageWh(const ush* __restrict__ Wh, int j, int kb,
                                        int w, int lane, ush* Ws)
{
    #pragma unroll
    for (int c8 = 0; c8 < 4; c8++) {
        int s = (c8 * 4 + w) * 64 + lane;
        int r = s >> 4, scc = (s & 15) ^ (r & 7);
        gload16(Wh + ((size_t)((r >> 4) * 1024 + j * 16 + (r & 15))) * 1024 + kb + scc * 8,
                Ws + (size_t)(c8 * 4 + w) * 512);
    }
}

__device__ __forceinline__ void lstm_step2(
    const ush* __restrict__ hsrc, int hstride, ush* __restrict__ hdst, int dstride,
    const ush* __restrict__ gx,
    float Bi, float Bf, float Bo, float Bc, float& creg,
    ush (*Whs)[8192], ush (*AsL)[2048],
    int rg, int j, int tid, unsigned* bar, unsigned target)
{
    const int w = tid >> 6, lane = tid & 63;
    const int r = tid >> 4, sl = tid & 15;      // (local row, slot/cc)
    const int gb = rg * 16 + r;                 // global batch row
    const int gcc = j * 16 + sl;                // global hidden col

    // Gx prefetch (consumed in epilogue; latency hidden under MFMA)
    const ush* gxr = gx + (size_t)gb * 4096 + gcc;
    ush gxi = gxr[0], gxf = gxr[1024], gxo = gxr[2048], gxc = gxr[3072];

    // A-tile stage: [16 rows][1024] as 8 chunks [16][128], slot-XOR swizzle.
    if (hsrc) {
        uint4 ra[8];
        const ush* rowp = hsrc + (size_t)gb * hstride;
        #pragma unroll
        for (int ch = 0; ch < 8; ch++)
            ra[ch] = *reinterpret_cast<const uint4*>(rowp + ch * 128 + sl * 8);
        #pragma unroll
        for (int ch = 0; ch < 8; ch++)
            *reinterpret_cast<uint4*>(&AsL[ch][r * 128 + (sl ^ (r & 7)) * 8]) = ra[ch];
    } else {
        uint4 z = {0, 0, 0, 0};
        #pragma unroll
        for (int ch = 0; ch < 8; ch++)
            *reinterpret_cast<uint4*>(&AsL[ch][r * 128 + sl * 8]) = z;
    }
    __syncthreads();

    // gate-per-wave MFMA: wave w = gate w, [16 rows]x[16 cc], K=1024
    f32x4 acc = {};
    #pragma unroll
    for (int ch = 0; ch < 8; ch++) {
        #pragma unroll
        for (int kw = 0; kw < 4; kw++) {
            int colo = kw * 32 + (lane >> 4) * 8;
            int ar = lane & 15;
            f16x8 af = *(const f16x8*)&AsL[ch][(ar * 128 + colo) ^ ((ar & 7) << 3)];
            int br = w * 16 + (lane & 15);
            f16x8 bfv = *(const f16x8*)&Whs[ch][(br * 128 + colo) ^ ((br & 7) << 3)];
            acc = __builtin_amdgcn_mfma_f32_16x16x32_f16(af, bfv, acc, 0, 0, 0);
        }
    }
    __syncthreads();                 // all waves done reading AsL
    float* zb = (float*)AsL;         // 4 KB z-exchange aliases A-tile
    #pragma unroll
    for (int rr = 0; rr < 4; rr++)
        zb[(w * 16 + (lane >> 4) * 4 + rr) * 16 + (lane & 15)] = acc[rr];
    __syncthreads();

    // elementwise epilogue: thread owns (gb, gcc); c in register
    float zi = zb[(r) * 16 + sl]      + Bi + h2f(gxi);
    float zf = zb[(16 + r) * 16 + sl] + Bf + h2f(gxf);
    float zo = zb[(32 + r) * 16 + sl] + Bo + h2f(gxo);
    float zc = zb[(48 + r) * 16 + sl] + Bc + h2f(gxc);
    float F = sigm(zf), I = sigm(zi), O = sigm(zo), G = tanhf(zc);
    creg = F * creg + I * G;
    float hn = O * tanhf(creg);
    unsigned hv = (unsigned)f2h(hn);
    unsigned other = __shfl_xor(hv, 1, 64);   // pair adjacent cc
    if ((lane & 1) == 0)
        st_agent_u32(hdst + (size_t)gb * dstride + gcc, hv | (other << 16));

    gbar(bar, target);
}

__global__ __launch_bounds__(256) void recurrent_all(RecArgs a)
{
    __shared__ ush Whs[8][8192];   // 128 KiB resident weight slice
    __shared__ ush AsL[8][2048];   // 32 KiB A-tile (aliased by z-exchange)
    const int bid = blockIdx.x;
    const int rg = bid >> 6;       // row-group 0..3 (contiguous in dispatch)
    const int j = bid & 63;        // col-group: hidden cols j*16..j*16+15
    const int tid = threadIdx.x;
    const int w = tid >> 6, lane = tid & 63;
    const int gcc = j * 16 + (tid & 15);
    unsigned* bar = a.bar + rg * 64;   // 256 B apart
    unsigned nb = 0;
    float creg = 0.f;

    // ---- encoder ----
    for (int ch = 0; ch < 8; ch++) stageWh(a.Whe, j, ch * 128, w, lane, Whs[ch]);
    {
        float Bi = a.ebi[gcc], Bf = a.ebf[gcc], Bo = a.ebo[gcc], Bc = a.ebc[gcc];
        for (int t = 0; t < TXX; t++) {
            const ush* hsrc = (t == 0) ? nullptr : a.enc16 + (size_t)(t - 1) * 65536;
            lstm_step2(hsrc, 1024, a.enc16 + (size_t)t * 65536, 1024,
                       a.Gxe + (size_t)t * 262144, Bi, Bf, Bo, Bc, creg,
                       Whs, AsL, rg, j, tid, bar, ++nb * 64u);
        }
    }
    // ---- decoder ----
    for (int ch = 0; ch < 8; ch++) stageWh(a.Whd, j, ch * 128, w, lane, Whs[ch]);
    {
        float Bi = a.dbi[gcc], Bf = a.dbf[gcc], Bo = a.dbo[gcc], Bc = a.dbc[gcc];
        for (int s = 0; s < NSS; s++) {
            const ush* hsrc = (s == 0) ? a.enc16 + (size_t)127 * 65536
                                       : a.Hcat + (size_t)(s - 1) * 64 * 2048;
            int hstride = (s == 0) ? 1024 : 2048;
            lstm_step2(hsrc, hstride, a.Hcat + (size_t)s * 64 * 2048, 2048,
                       a.Gxd + (size_t)s * 262144, Bi, Bf, Bo, Bc, creg,
                       Whs, AsL, rg, j, tid, bar, ++nb * 64u);
        }
    }
}

// ---------------------------------------------------------------------------
// Tiled attention: one block per (s-tile of 8, b). q-tile + e-vector in LDS;
// each e[t] load reused 8x in scores (LDS) and 8x in ctx (registers).
// Replaces 3008-block attn_batched (~8x less L2 traffic, 384 blocks).
// ---------------------------------------------------------------------------
__global__ __launch_bounds__(256) void attn_tiled(
    const float* __restrict__ q, const ush* __restrict__ enc16,
    ush* __restrict__ Hcat)
{
    __shared__ float qs[8][1024];   // 32 KB
    __shared__ float ev[2][1024];   // 8 KB double-buffered e-vector
    __shared__ float sc[8][130];    // scores -> normalized weights
    const int st = blockIdx.x, b = blockIdx.y;
    const int s0 = st * 8;
    const int tid = threadIdx.x;

    // load 8 q rows (guard s < 47; pad rows read as 0)
    for (int idx = tid; idx < 8 * 1024; idx += 256) {
        int slq = idx >> 10, h = idx & 1023;
        int s = s0 + slq;
        qs[slq][h] = (s < NSS) ? q[((size_t)s * 64 + b) * 1024 + h] : 0.f;
    }
    // prologue: stage ev[0] for t=0
    {
        int h0 = tid * 4;
        ushx4 e4 = *reinterpret_cast<const ushx4*>(
            enc16 + ((size_t)0 * 64 + b) * 1024 + h0);
        ev[0][h0] = h2f(e4[0]); ev[0][h0 + 1] = h2f(e4[1]);
        ev[0][h0 + 2] = h2f(e4[2]); ev[0][h0 + 3] = h2f(e4[3]);
    }
    const int slc = tid >> 5, l32 = tid & 31;
    for (int t = 0; t < 128; t++) {
        __syncthreads();
        if (t + 1 < 128) {
            int h0 = tid * 4;
            ushx4 e4 = *reinterpret_cast<const ushx4*>(
                enc16 + ((size_t)(t + 1) * 64 + b) * 1024 + h0);
            float* dst = ev[(t + 1) & 1];
            dst[h0] = h2f(e4[0]); dst[h0 + 1] = h2f(e4[1]);
            dst[h0 + 2] = h2f(e4[2]); dst[h0 + 3] = h2f(e4[3]);
        }
        const float* e = ev[t & 1];
        float p = 0.f;
        #pragma unroll
        for (int k = 0; k < 32; k++) p += qs[slc][l32 + 32 * k] * e[l32 + 32 * k];
        #pragma unroll
        for (int o = 16; o > 0; o >>= 1) p += __shfl_down(p, o, 32);
        if (l32 == 0) sc[slc][t] = p;
    }
    __syncthreads();

    // softmax per s: wave w handles s = w and s = w+4
    {
        int wv = tid >> 6, lane = tid & 63;
        #pragma unroll
        for (int half = 0; half < 2; half++) {
            int s = wv + half * 4;
            float v0 = sc[s][lane], v1 = sc[s][lane + 64];
            float m = fmaxf(v0, v1);
            #pragma unroll
            for (int o = 32; o > 0; o >>= 1) m = fmaxf(m, __shfl_down(m, o, 64));
            m = __shfl(m, 0, 64);
            float e0 = expf(v0 - m), e1 = expf(v1 - m);
            float sum = e0 + e1;
            #pragma unroll
            for (int o = 32; o > 0; o >>= 1) sum += __shfl_down(sum, o, 64);
            sum = __shfl(sum, 0, 64);
            float inv = 1.f / sum;
            sc[s][lane] = e0 * inv;
            sc[s][lane + 64] = e1 * inv;
        }
    }
    __syncthreads();

    // ctx: thread owns h0..h0+3 for all 8 s (32 acc registers)
    int h0 = tid * 4;
    float acc[8][4] = {};
    for (int t = 0; t < 128; t++) {
        ushx4 e4 = *reinterpret_cast<const ushx4*>(
            enc16 + ((size_t)t * 64 + b) * 1024 + h0);
        float e0 = h2f(e4[0]), e1 = h2f(e4[1]), e2 = h2f(e4[2]), e3 = h2f(e4[3]);
        #pragma unroll
        for (int s = 0; s < 8; s++) {
            float av = sc[s][t];
            acc[s][0] += av * e0; acc[s][1] += av * e1;
            acc[s][2] += av * e2; acc[s][3] += av * e3;
        }
    }
    #pragma unroll
    for (int s = 0; s < 8; s++) {
        int gs = s0 + s;
        if (gs < NSS) {
            ushx4 o = {f2h(acc[s][0]), f2h(acc[s][1]),
                       f2h(acc[s][2]), f2h(acc[s][3])};
            *reinterpret_cast<ushx4*>(
                &Hcat[((size_t)gs * 64 + b) * 2048 + 1024 + h0]) = o;
        }
    }
}

// ---------------------------------------------------------------------------
extern "C" void kernel_launch(void* const* d_in, const int* in_sizes, int n_in,
                              void* d_out, int out_size, void* d_ws, size_t ws_size,
                              hipStream_t stream)
{
    const int*   x       = (const int*)d_in[0];
    const int*   y       = (const int*)d_in[1];
    const float* enc_emb = (const float*)d_in[2];
    const float* dec_emb = (const float*)d_in[3];
    const float* encW[4] = {(const float*)d_in[4], (const float*)d_in[6],
                            (const float*)d_in[8], (const float*)d_in[10]};
    const float* encB[4] = {(const float*)d_in[5], (const float*)d_in[7],
                            (const float*)d_in[9], (const float*)d_in[11]};
    const float* decW[4] = {(const float*)d_in[12], (const float*)d_in[14],
                            (const float*)d_in[16], (const float*)d_in[18]};
    const float* decB[4] = {(const float*)d_in[13], (const float*)d_in[15],
                            (const float*)d_in[17], (const float*)d_in[19]};
    const float* attn_w  = (const float*)d_in[20];
    const float* attn_b  = (const float*)d_in[21];
    const float* lin_w   = (const float*)d_in[22];
    const float* lin_b   = (const float*)d_in[23];
    const float* out_w   = (const float*)d_in[24];
    const float* out_b   = (const float*)d_in[25];

    // ws layout: same proven extents (high-water 30408704 f)
    float* ws = (float*)d_ws;
    ush*   preh   = (ush*)(ws + 393216);         // 3072x1024 ush (3008 valid)
    ush*   enc16  = (ush*)(ws + 1966080);        // 128x64x1024 ush
    ush*   Wt     = (ush*)(ws + 6160384);        // 32000x1024 ush
    ush*   Whe    = (ush*)(ws + 22544384);       // 4096x1024 ush
    ush*   Whd    = (ush*)(ws + 24641536);
    ush*   Wxe    = (ush*)(ws + 26738688);       // 4096x512 ush
    ush*   Wxd    = (ush*)(ws + 27787264);
    ush*   attn_t = (ush*)(ws + 28835840);       // 1024x1024 ush
    ush*   lin_t  = (ush*)(ws + 29360128);       // 1024x2048 ush
    // 4 row-group barrier counters in preh PAD rows (zeroed each launch,
    // only read back as discarded guarded A-pad) — proven location.
    unsigned* bar = (unsigned*)(preh + (size_t)3008 * 1024);

    // dead-before-outproj scratch in d_out
    ush*   Gx_enc = (ush*)d_out;                     // 8192*4096
    ush*   Gx_dec = Gx_enc + (size_t)8192 * 4096;    // 3072*4096
    ush*   Xe     = Gx_dec + (size_t)3072 * 4096;    // 8192*512
    ush*   Ye     = Xe + (size_t)8192 * 512;         // 3072*512
    ush*   Hcat   = Ye + (size_t)3072 * 512;         // 3072*2048
    float* qbuf   = (float*)(Hcat + (size_t)3072 * 2048);  // 3072*1024 f32

    hipMemsetAsync(preh, 0, (size_t)3072 * 1024 * 2, stream); // pad + counters

    // ---- weight prep ----
    transpose_w<<<dim3(VV / 32, 32), 256, 0, stream>>>(out_w, Wt, VV, HH);
    transpose_w<<<dim3(32, 32), 256, 0, stream>>>(attn_w, attn_t, HH, HH);
    transpose_w<<<dim3(32, 64), 256, 0, stream>>>(lin_w, lin_t, HH, 2048);
    for (int g = 0; g < 4; g++) {
        transpose_w<<<dim3(32, 32), 256, 0, stream>>>(
            encW[g] + (size_t)EE * HH, Whe + (size_t)g * 1024 * 1024, HH, HH);
        transpose_w<<<dim3(32, 32), 256, 0, stream>>>(
            decW[g] + (size_t)EE * HH, Whd + (size_t)g * 1024 * 1024, HH, HH);
        transpose_w<<<dim3(32, 16), 256, 0, stream>>>(
            encW[g], Wxe + (size_t)g * 1024 * 512, HH, EE);
        transpose_w<<<dim3(32, 16), 256, 0, stream>>>(
            decW[g], Wxd + (size_t)g * 1024 * 512, HH, EE);
    }

    // ---- embedding gathers ----
    gather_emb<<<dim3(2048), 256, 0, stream>>>(enc_emb, x, Xe, TXX, TXX);
    gather_emb<<<dim3(768), 256, 0, stream>>>(dec_emb, y, Ye, TYY, NSS);

    // ---- x-side gate precompute ----
    gemm_f16<2><<<dim3(64, 32), 256, 0, stream>>>(
        Xe, EE, Wxe, nullptr, Gx_enc, EE, 4096, 8192);
    gemm_f16<2><<<dim3(24, 32), 256, 0, stream>>>(
        Ye, EE, Wxd, nullptr, Gx_dec, EE, 4096, 3072);

    // ---- persistent recurrent kernel (plain launch; 256 blocks, 1/CU) ----
    RecArgs ra;
    ra.Whe = Whe; ra.Whd = Whd; ra.Gxe = Gx_enc; ra.Gxd = Gx_dec;
    ra.ebi = encB[0]; ra.ebf = encB[1]; ra.ebo = encB[2]; ra.ebc = encB[3];
    ra.dbi = decB[0]; ra.dbf = decB[1]; ra.dbo = decB[2]; ra.dbc = decB[3];
    ra.enc16 = enc16; ra.Hcat = Hcat; ra.bar = bar;
    recurrent_all<<<dim3(256), dim3(256), 0, stream>>>(ra);

    // ---- post-recurrent batched phases ----
    gemm_f16<0><<<dim3(24, 8), 256, 0, stream>>>(
        Hcat, 2048, attn_t, attn_b, qbuf, HH, HH, 3008);
    attn_tiled<<<dim3(6, 64), 256, 0, stream>>>(qbuf, enc16, Hcat);
    gemm_f16<3><<<dim3(24, 8), 256, 0, stream>>>(
        Hcat, 2048, lin_t, lin_b, preh, 2048, HH, 3008);

    // ---- output projection ----
    gemm_f16<1><<<dim3(24, VV / 128), 256, 0, stream>>>(
        preh, HH, Wt, out_b, d_out, HH, VV, 3008);
}

// Round 12
// 1616.950 us; speedup vs baseline: 1.1102x; 1.0285x over previous
//
#include <hip/hip_runtime.h>
#include <hip/hip_bf16.h>
#include <cstddef>

#define BB 64
#define TXX 128
#define TYY 48
#define NSS 47
#define EE 512
#define HH 1024
#define VV 32000

typedef _Float16 f16x8 __attribute__((ext_vector_type(8)));
typedef float f32x4 __attribute__((ext_vector_type(4)));
typedef unsigned short ush;
typedef ush ushx4 __attribute__((ext_vector_type(4)));

__device__ __forceinline__ ush f2h(float x) {
    _Float16 h = (_Float16)x;
    return __builtin_bit_cast(ush, h);
}
__device__ __forceinline__ float h2f(ush u) {
    return (float)__builtin_bit_cast(_Float16, u);
}
// cached global->LDS DMA (proven rounds 1-11)
__device__ __forceinline__ void gload16(const void* g, void* l) {
    __builtin_amdgcn_global_load_lds(
        (const __attribute__((address_space(1))) unsigned int*)g,
        (__attribute__((address_space(3))) unsigned int*)l, 16, 0, 0);
}
__device__ __forceinline__ void st_agent_u32(void* p, unsigned v) {
    __hip_atomic_store((unsigned*)p, v, __ATOMIC_RELAXED, __HIP_MEMORY_SCOPE_AGENT);
}
__device__ __forceinline__ float sigm(float x) { return 1.f / (1.f + expf(-x)); }

// Round-9 proven relaxed row-group barrier (single counter + fetch_add).
__device__ __forceinline__ void gbar(unsigned* bar, unsigned target) {
    asm volatile("s_waitcnt vmcnt(0)" ::: "memory");
    __syncthreads();
    if (threadIdx.x == 0) {
        __hip_atomic_fetch_add(bar, 1u, __ATOMIC_RELAXED, __HIP_MEMORY_SCOPE_AGENT);
        while (__hip_atomic_load(bar, __ATOMIC_RELAXED, __HIP_MEMORY_SCOPE_AGENT) < target) {
            __builtin_amdgcn_s_sleep(2);
        }
    }
    __syncthreads();
}

// ---------------------------------------------------------------------------
// Transpose + f32->f16: shared body; single and batched-8 variants.
// ---------------------------------------------------------------------------
__device__ __forceinline__ void transpose_body(
    const float* __restrict__ W, ush* __restrict__ Wt, int ldW, int ldT)
{
    __shared__ float t[32][33];
    int v0 = blockIdx.x * 32, k0 = blockIdx.y * 32;
    int tv = threadIdx.x & 31, tk = threadIdx.x >> 5;
    #pragma unroll
    for (int i = 0; i < 4; i++) {
        int k = tk * 4 + i;
        t[k][tv] = W[(size_t)(k0 + k) * ldW + v0 + tv];
    }
    __syncthreads();
    #pragma unroll
    for (int i = 0; i < 4; i++) {
        int v = tk * 4 + i;
        Wt[(size_t)(v0 + v) * ldT + k0 + tv] = f2h(t[tv][v]);
    }
}

__global__ __launch_bounds__(256) void transpose_w(
    const float* __restrict__ W, ush* __restrict__ Wt, int ldW, int ldT)
{
    transpose_body(W, Wt, ldW, ldT);
}

struct TWArgs { const float* src[8]; ush* dst[8]; };
__global__ __launch_bounds__(256) void transpose_w8(TWArgs a, int ldW, int ldT)
{
    int g = blockIdx.z;
    transpose_body(a.src[g], a.dst[g], ldW, ldT);
}

// ---------------------------------------------------------------------------
// Embedding gather + f16 convert (unchanged)
// ---------------------------------------------------------------------------
__global__ __launch_bounds__(256) void gather_emb(
    const float* __restrict__ emb, const int* __restrict__ tok,
    ush* __restrict__ out, int tokld, int tmax)
{
    int i = blockIdx.x * 256 + threadIdx.x;
    int r = i >> 6, kq = (i & 63) * 8;
    int t = r >> 6, b = r & 63;
    ush v[8];
    if (t < tmax) {
        int tk = tok[b * tokld + t];
        const float* e = emb + (size_t)tk * EE + kq;
        #pragma unroll
        for (int j = 0; j < 8; j++) v[j] = f2h(e[j]);
    } else {
        #pragma unroll
        for (int j = 0; j < 8; j++) v[j] = 0;
    }
    *reinterpret_cast<f16x8*>(&out[(size_t)r * EE + kq]) =
        *reinterpret_cast<f16x8*>(v);
}

// ---------------------------------------------------------------------------
// f16 MFMA GEMM, 128x128 tile + XCD-aware block swizzle (kept). MODE:
//  0: f32 C row-major + bias; 1: out-proj permute + bias; 2: f16 C;
//  3: f16 C, tanh(acc+bias). Guards row<Mvalid (MODE 1: row<3008).
// ---------------------------------------------------------------------------
template <int MODE>
__global__ __launch_bounds__(256) void gemm_f16(
    const ush* __restrict__ A, int lda, const ush* __restrict__ Bt,
    const float* __restrict__ bias, void* __restrict__ Cv,
    int K, int Nld, int Mvalid)
{
    __shared__ ush As[128 * 64];
    __shared__ ush Bs[128 * 64];
    const int tid = threadIdx.x;
    const int lane = tid & 63;
    const int w = tid >> 6;
    const int wm = w >> 1, wn = w & 1;
    const int nwg = gridDim.x * gridDim.y;
    const int orig = blockIdx.y * gridDim.x + blockIdx.x;
    const int swz = (orig & 7) * (nwg >> 3) + (orig >> 3);
    const int m0 = (swz % gridDim.x) * 128;
    const int n0 = (swz / gridDim.x) * 128;

    f32x4 acc[4][4] = {};
    const int srow = w * 32 + (lane >> 3);
    const int skoff = (lane & 7) * 8;

    for (int kb = 0; kb < K; kb += 64) {
        #pragma unroll
        for (int c = 0; c < 4; c++) {
            const ush* ga = A + (size_t)(m0 + srow + c * 8) * lda + kb + skoff;
            gload16(ga, &As[(w * 4 + c) * 512]);
        }
        #pragma unroll
        for (int c = 0; c < 4; c++) {
            const ush* gb = Bt + (size_t)(n0 + srow + c * 8) * K + kb + skoff;
            gload16(gb, &Bs[(w * 4 + c) * 512]);
        }
        __syncthreads();

        #pragma unroll
        for (int kw = 0; kw < 2; kw++) {
            const int koff = kw * 32 + (lane >> 4) * 8;
            f16x8 af[4], bf[4];
            #pragma unroll
            for (int m = 0; m < 4; m++)
                af[m] = *(const f16x8*)&As[(wm * 64 + m * 16 + (lane & 15)) * 64 + koff];
            #pragma unroll
            for (int n = 0; n < 4; n++)
                bf[n] = *(const f16x8*)&Bs[(wn * 64 + n * 16 + (lane & 15)) * 64 + koff];
            #pragma unroll
            for (int m = 0; m < 4; m++)
                #pragma unroll
                for (int n = 0; n < 4; n++)
                    acc[m][n] = __builtin_amdgcn_mfma_f32_16x16x32_f16(
                        af[m], bf[n], acc[m][n], 0, 0, 0);
        }
        __syncthreads();
    }

    #pragma unroll
    for (int n = 0; n < 4; n++) {
        int v = n0 + wn * 64 + n * 16 + (lane & 15);
        float bs = (MODE == 2) ? 0.f : (bias ? bias[v] : 0.f);
        #pragma unroll
        for (int m = 0; m < 4; m++) {
            int rbase = m0 + wm * 64 + m * 16 + (lane >> 4) * 4;
            #pragma unroll
            for (int r = 0; r < 4; r++) {
                int row = rbase + r;
                float val = acc[m][n][r] + bs;
                if (MODE == 1) {
                    if (row < 3008) {
                        int b = row & 63, s = row >> 6;
                        ((float*)Cv)[((size_t)b * NSS + s) * VV + v] = val;
                    }
                } else if (MODE == 0) {
                    if (row < Mvalid) ((float*)Cv)[(size_t)row * Nld + v] = val;
                } else if (MODE == 2) {
                    if (row < Mvalid) ((ush*)Cv)[(size_t)row * Nld + v] = f2h(val);
                } else {
                    if (row < Mvalid)
                        ((ush*)Cv)[(size_t)row * Nld + v] = f2h(tanhf(val));
                }
            }
        }
    }
}

// ===========================================================================
// Persistent recurrent kernel (round-9 proven, untouched): 256 blocks =
// 4 row-groups (16 batch rows) x 64 col-groups (16 cols x 4 gates).
// ===========================================================================
struct RecArgs {
    const ush *Whe, *Whd, *Gxe, *Gxd;
    const float *ebi, *ebf, *ebo, *ebc;
    const float *dbi, *dbf, *dbo, *dbc;
    ush *enc16, *Hcat;
    unsigned* bar;
};

__device__ __forceinline__ void stageWh(const ush* __restrict__ Wh, int j, int kb,
                                        int w, int lane, ush* Ws)
{
    #pragma unroll
    for (int c8 = 0; c8 < 4; c8++) {
        int s = (c8 * 4 + w) * 64 + lane;
        int r = s >> 4, scc = (s & 15) ^ (r & 7);
        gload16(Wh + ((size_t)((r >> 4) * 1024 + j * 16 + (r & 15))) * 1024 + kb + scc * 8,
                Ws + (size_t)(c8 * 4 + w) * 512);
    }
}

__device__ __forceinline__ void lstm_step2(
    const ush* __restrict__ hsrc, int hstride, ush* __restrict__ hdst, int dstride,
    const ush* __restrict__ gx,
    float Bi, float Bf, float Bo, float Bc, float& creg,
    ush (*Whs)[8192], ush (*AsL)[2048],
    int rg, int j, int tid, unsigned* bar, unsigned target)
{
    const int w = tid >> 6, lane = tid & 63;
    const int r = tid >> 4, sl = tid & 15;      // (local row, slot/cc)
    const int gb = rg * 16 + r;                 // global batch row
    const int gcc = j * 16 + sl;                // global hidden col

    const ush* gxr = gx + (size_t)gb * 4096 + gcc;
    ush gxi = gxr[0], gxf = gxr[1024], gxo = gxr[2048], gxc = gxr[3072];

    if (hsrc) {
        uint4 ra[8];
        const ush* rowp = hsrc + (size_t)gb * hstride;
        #pragma unroll
        for (int ch = 0; ch < 8; ch++)
            ra[ch] = *reinterpret_cast<const uint4*>(rowp + ch * 128 + sl * 8);
        #pragma unroll
        for (int ch = 0; ch < 8; ch++)
            *reinterpret_cast<uint4*>(&AsL[ch][r * 128 + (sl ^ (r & 7)) * 8]) = ra[ch];
    } else {
        uint4 z = {0, 0, 0, 0};
        #pragma unroll
        for (int ch = 0; ch < 8; ch++)
            *reinterpret_cast<uint4*>(&AsL[ch][r * 128 + sl * 8]) = z;
    }
    __syncthreads();

    f32x4 acc = {};
    #pragma unroll
    for (int ch = 0; ch < 8; ch++) {
        #pragma unroll
        for (int kw = 0; kw < 4; kw++) {
            int colo = kw * 32 + (lane >> 4) * 8;
            int ar = lane & 15;
            f16x8 af = *(const f16x8*)&AsL[ch][(ar * 128 + colo) ^ ((ar & 7) << 3)];
            int br = w * 16 + (lane & 15);
            f16x8 bfv = *(const f16x8*)&Whs[ch][(br * 128 + colo) ^ ((br & 7) << 3)];
            acc = __builtin_amdgcn_mfma_f32_16x16x32_f16(af, bfv, acc, 0, 0, 0);
        }
    }
    __syncthreads();
    float* zb = (float*)AsL;
    #pragma unroll
    for (int rr = 0; rr < 4; rr++)
        zb[(w * 16 + (lane >> 4) * 4 + rr) * 16 + (lane & 15)] = acc[rr];
    __syncthreads();

    float zi = zb[(r) * 16 + sl]      + Bi + h2f(gxi);
    float zf = zb[(16 + r) * 16 + sl] + Bf + h2f(gxf);
    float zo = zb[(32 + r) * 16 + sl] + Bo + h2f(gxo);
    float zc = zb[(48 + r) * 16 + sl] + Bc + h2f(gxc);
    float F = sigm(zf), I = sigm(zi), O = sigm(zo), G = tanhf(zc);
    creg = F * creg + I * G;
    float hn = O * tanhf(creg);
    unsigned hv = (unsigned)f2h(hn);
    unsigned other = __shfl_xor(hv, 1, 64);
    if ((lane & 1) == 0)
        st_agent_u32(hdst + (size_t)gb * dstride + gcc, hv | (other << 16));

    gbar(bar, target);
}

__global__ __launch_bounds__(256) void recurrent_all(RecArgs a)
{
    __shared__ ush Whs[8][8192];   // 128 KiB resident weight slice
    __shared__ ush AsL[8][2048];   // 32 KiB A-tile (aliased by z-exchange)
    const int bid = blockIdx.x;
    const int rg = bid >> 6;
    const int j = bid & 63;
    const int tid = threadIdx.x;
    const int w = tid >> 6, lane = tid & 63;
    const int gcc = j * 16 + (tid & 15);
    unsigned* bar = a.bar + rg * 64;
    unsigned nb = 0;
    float creg = 0.f;

    for (int ch = 0; ch < 8; ch++) stageWh(a.Whe, j, ch * 128, w, lane, Whs[ch]);
    {
        float Bi = a.ebi[gcc], Bf = a.ebf[gcc], Bo = a.ebo[gcc], Bc = a.ebc[gcc];
        for (int t = 0; t < TXX; t++) {
            const ush* hsrc = (t == 0) ? nullptr : a.enc16 + (size_t)(t - 1) * 65536;
            lstm_step2(hsrc, 1024, a.enc16 + (size_t)t * 65536, 1024,
                       a.Gxe + (size_t)t * 262144, Bi, Bf, Bo, Bc, creg,
                       Whs, AsL, rg, j, tid, bar, ++nb * 64u);
        }
    }
    for (int ch = 0; ch < 8; ch++) stageWh(a.Whd, j, ch * 128, w, lane, Whs[ch]);
    {
        float Bi = a.dbi[gcc], Bf = a.dbf[gcc], Bo = a.dbo[gcc], Bc = a.dbc[gcc];
        for (int s = 0; s < NSS; s++) {
            const ush* hsrc = (s == 0) ? a.enc16 + (size_t)127 * 65536
                                       : a.Hcat + (size_t)(s - 1) * 64 * 2048;
            int hstride = (s == 0) ? 1024 : 2048;
            lstm_step2(hsrc, hstride, a.Hcat + (size_t)s * 64 * 2048, 2048,
                       a.Gxd + (size_t)s * 262144, Bi, Bf, Bo, Bc, creg,
                       Whs, AsL, rg, j, tid, bar, ++nb * 64u);
        }
    }
}

// ---------------------------------------------------------------------------
// Batched attention (round-10 proven): one block per (s, b).
// ---------------------------------------------------------------------------
__global__ __launch_bounds__(256) void attn_batched(
    const float* __restrict__ q, const ush* __restrict__ enc16,
    ush* __restrict__ Hcat)
{
    int s = blockIdx.x, b = blockIdx.y;
    int row = s * 64 + b;
    int tid = threadIdx.x;
    __shared__ float qs[1024];
    __shared__ float sc[130];

    for (int i = tid; i < 1024; i += 256) qs[i] = q[(size_t)row * 1024 + i];
    __syncthreads();

    int wave = tid >> 6, lane = tid & 63;
    for (int i = 0; i < 32; i++) {
        int t = wave * 32 + i;
        const ush* e = enc16 + ((size_t)t * 64 + b) * 1024;
        float sv = 0.f;
        #pragma unroll
        for (int jj = 0; jj < 16; jj++) sv += qs[lane + jj * 64] * h2f(e[lane + jj * 64]);
        #pragma unroll
        for (int o = 32; o > 0; o >>= 1) sv += __shfl_down(sv, o, 64);
        if (lane == 0) sc[t] = sv;
    }
    __syncthreads();

    if (wave == 0) {
        float v = fmaxf(sc[lane], sc[lane + 64]);
        #pragma unroll
        for (int o = 32; o > 0; o >>= 1) v = fmaxf(v, __shfl_down(v, o, 64));
        if (lane == 0) sc[128] = v;
    }
    __syncthreads();
    float mx = sc[128];
    if (wave == 0) {
        float e0 = expf(sc[lane] - mx), e1 = expf(sc[lane + 64] - mx);
        sc[lane] = e0; sc[lane + 64] = e1;
        float v = e0 + e1;
        #pragma unroll
        for (int o = 32; o > 0; o >>= 1) v += __shfl_down(v, o, 64);
        if (lane == 0) sc[129] = v;
    }
    __syncthreads();
    float inv = 1.f / sc[129];

    int h0 = tid * 4;
    float a0 = 0.f, a1 = 0.f, a2 = 0.f, a3 = 0.f;
    #pragma unroll 4
    for (int t = 0; t < 128; t++) {
        float av = sc[t] * inv;
        ushx4 ev = *reinterpret_cast<const ushx4*>(
            enc16 + ((size_t)t * 64 + b) * 1024 + h0);
        a0 += av * h2f(ev[0]); a1 += av * h2f(ev[1]);
        a2 += av * h2f(ev[2]); a3 += av * h2f(ev[3]);
    }
    ushx4 o = {f2h(a0), f2h(a1), f2h(a2), f2h(a3)};
    *reinterpret_cast<ushx4*>(&Hcat[(size_t)row * 2048 + 1024 + h0]) = o;
}

// ---------------------------------------------------------------------------
extern "C" void kernel_launch(void* const* d_in, const int* in_sizes, int n_in,
                              void* d_out, int out_size, void* d_ws, size_t ws_size,
                              hipStream_t stream)
{
    const int*   x       = (const int*)d_in[0];
    const int*   y       = (const int*)d_in[1];
    const float* enc_emb = (const float*)d_in[2];
    const float* dec_emb = (const float*)d_in[3];
    const float* encW[4] = {(const float*)d_in[4], (const float*)d_in[6],
                            (const float*)d_in[8], (const float*)d_in[10]};
    const float* encB[4] = {(const float*)d_in[5], (const float*)d_in[7],
                            (const float*)d_in[9], (const float*)d_in[11]};
    const float* decW[4] = {(const float*)d_in[12], (const float*)d_in[14],
                            (const float*)d_in[16], (const float*)d_in[18]};
    const float* decB[4] = {(const float*)d_in[13], (const float*)d_in[15],
                            (const float*)d_in[17], (const float*)d_in[19]};
    const float* attn_w  = (const float*)d_in[20];
    const float* attn_b  = (const float*)d_in[21];
    const float* lin_w   = (const float*)d_in[22];
    const float* lin_b   = (const float*)d_in[23];
    const float* out_w   = (const float*)d_in[24];
    const float* out_b   = (const float*)d_in[25];

    // ws layout: proven extents (high-water 30408704 f)
    float* ws = (float*)d_ws;
    ush*   preh   = (ush*)(ws + 393216);         // 3072x1024 ush (3008 valid)
    ush*   enc16  = (ush*)(ws + 1966080);        // 128x64x1024 ush
    ush*   Wt     = (ush*)(ws + 6160384);        // 32000x1024 ush
    ush*   Whe    = (ush*)(ws + 22544384);       // 4096x1024 ush
    ush*   Whd    = (ush*)(ws + 24641536);
    ush*   Wxe    = (ush*)(ws + 26738688);       // 4096x512 ush
    ush*   Wxd    = (ush*)(ws + 27787264);
    ush*   attn_t = (ush*)(ws + 28835840);       // 1024x1024 ush
    ush*   lin_t  = (ush*)(ws + 29360128);       // 1024x2048 ush
    unsigned* bar = (unsigned*)(preh + (size_t)3008 * 1024);  // pad rows

    // dead-before-outproj scratch in d_out
    ush*   Gx_enc = (ush*)d_out;                     // 8192*4096
    ush*   Gx_dec = Gx_enc + (size_t)8192 * 4096;    // 3072*4096
    ush*   Xe     = Gx_dec + (size_t)3072 * 4096;    // 8192*512
    ush*   Ye     = Xe + (size_t)8192 * 512;         // 3072*512
    ush*   Hcat   = Ye + (size_t)3072 * 512;         // 3072*2048
    float* qbuf   = (float*)(Hcat + (size_t)3072 * 2048);  // 3072*1024 f32

    hipMemsetAsync(preh, 0, (size_t)3072 * 1024 * 2, stream); // pad + counters

    // ---- weight prep (5 launches instead of 19) ----
    transpose_w<<<dim3(VV / 32, 32), 256, 0, stream>>>(out_w, Wt, VV, HH);
    transpose_w<<<dim3(32, 32), 256, 0, stream>>>(attn_w, attn_t, HH, HH);
    transpose_w<<<dim3(32, 64), 256, 0, stream>>>(lin_w, lin_t, HH, 2048);
    {
        TWArgs wh, wx;
        for (int g = 0; g < 4; g++) {
            wh.src[g]     = encW[g] + (size_t)EE * HH;
            wh.dst[g]     = Whe + (size_t)g * 1024 * 1024;
            wh.src[4 + g] = decW[g] + (size_t)EE * HH;
            wh.dst[4 + g] = Whd + (size_t)g * 1024 * 1024;
            wx.src[g]     = encW[g];
            wx.dst[g]     = Wxe + (size_t)g * 1024 * 512;
            wx.src[4 + g] = decW[g];
            wx.dst[4 + g] = Wxd + (size_t)g * 1024 * 512;
        }
        transpose_w8<<<dim3(32, 32, 8), 256, 0, stream>>>(wh, HH, HH);
        transpose_w8<<<dim3(32, 16, 8), 256, 0, stream>>>(wx, HH, EE);
    }

    // ---- embedding gathers ----
    gather_emb<<<dim3(2048), 256, 0, stream>>>(enc_emb, x, Xe, TXX, TXX);
    gather_emb<<<dim3(768), 256, 0, stream>>>(dec_emb, y, Ye, TYY, NSS);

    // ---- x-side gate precompute ----
    gemm_f16<2><<<dim3(64, 32), 256, 0, stream>>>(
        Xe, EE, Wxe, nullptr, Gx_enc, EE, 4096, 8192);
    gemm_f16<2><<<dim3(24, 32), 256, 0, stream>>>(
        Ye, EE, Wxd, nullptr, Gx_dec, EE, 4096, 3072);

    // ---- persistent recurrent kernel (proven; untouched) ----
    RecArgs ra;
    ra.Whe = Whe; ra.Whd = Whd; ra.Gxe = Gx_enc; ra.Gxd = Gx_dec;
    ra.ebi = encB[0]; ra.ebf = encB[1]; ra.ebo = encB[2]; ra.ebc = encB[3];
    ra.dbi = decB[0]; ra.dbf = decB[1]; ra.dbo = decB[2]; ra.dbc = decB[3];
    ra.enc16 = enc16; ra.Hcat = Hcat; ra.bar = bar;
    recurrent_all<<<dim3(256), dim3(256), 0, stream>>>(ra);

    // ---- post-recurrent batched phases ----
    gemm_f16<0><<<dim3(24, 8), 256, 0, stream>>>(
        Hcat, 2048, attn_t, attn_b, qbuf, HH, HH, 3008);
    attn_batched<<<dim3(NSS, 64), 256, 0, stream>>>(qbuf, enc16, Hcat);
    gemm_f16<3><<<dim3(24, 8), 256, 0, stream>>>(
        Hcat, 2048, lin_t, lin_b, preh, 2048, HH, 3008);

    // ---- output projection ----
    gemm_f16<1><<<dim3(24, VV / 128), 256, 0, stream>>>(
        preh, HH, Wt, out_b, d_out, HH, VV, 3008);
}

// Round 13
// 1447.719 us; speedup vs baseline: 1.2400x; 1.1169x over previous
//
#include <hip/hip_runtime.h>
#include <hip/hip_bf16.h>
#include <cstddef>

#define BB 64
#define TXX 128
#define TYY 48
#define NSS 47
#define EE 512
#define HH 1024
#define VV 32000

typedef _Float16 f16x8 __attribute__((ext_vector_type(8)));
typedef float f32x4 __attribute__((ext_vector_type(4)));
typedef unsigned short ush;
typedef ush ushx4 __attribute__((ext_vector_type(4)));

__device__ __forceinline__ ush f2h(float x) {
    _Float16 h = (_Float16)x;
    return __builtin_bit_cast(ush, h);
}
__device__ __forceinline__ float h2f(ush u) {
    return (float)__builtin_bit_cast(_Float16, u);
}
// cached global->LDS DMA (proven rounds 1-12)
__device__ __forceinline__ void gload16(const void* g, void* l) {
    __builtin_amdgcn_global_load_lds(
        (const __attribute__((address_space(1))) unsigned int*)g,
        (__attribute__((address_space(3))) unsigned int*)l, 16, 0, 0);
}
__device__ __forceinline__ void st_agent_u32(void* p, unsigned v) {
    __hip_atomic_store((unsigned*)p, v, __ATOMIC_RELAXED, __HIP_MEMORY_SCOPE_AGENT);
}
__device__ __forceinline__ float sigm(float x) { return 1.f / (1.f + expf(-x)); }

// Round-9 proven relaxed row-group barrier (single counter + fetch_add).
__device__ __forceinline__ void gbar(unsigned* bar, unsigned target) {
    asm volatile("s_waitcnt vmcnt(0)" ::: "memory");
    __syncthreads();
    if (threadIdx.x == 0) {
        __hip_atomic_fetch_add(bar, 1u, __ATOMIC_RELAXED, __HIP_MEMORY_SCOPE_AGENT);
        while (__hip_atomic_load(bar, __ATOMIC_RELAXED, __HIP_MEMORY_SCOPE_AGENT) < target) {
            __builtin_amdgcn_s_sleep(2);
        }
    }
    __syncthreads();
}

// ---------------------------------------------------------------------------
// Transpose + f32->f16: shared body; single and batched-8 variants.
// ---------------------------------------------------------------------------
__device__ __forceinline__ void transpose_body(
    const float* __restrict__ W, ush* __restrict__ Wt, int ldW, int ldT)
{
    __shared__ float t[32][33];
    int v0 = blockIdx.x * 32, k0 = blockIdx.y * 32;
    int tv = threadIdx.x & 31, tk = threadIdx.x >> 5;
    #pragma unroll
    for (int i = 0; i < 4; i++) {
        int k = tk * 4 + i;
        t[k][tv] = W[(size_t)(k0 + k) * ldW + v0 + tv];
    }
    __syncthreads();
    #pragma unroll
    for (int i = 0; i < 4; i++) {
        int v = tk * 4 + i;
        Wt[(size_t)(v0 + v) * ldT + k0 + tv] = f2h(t[tv][v]);
    }
}

__global__ __launch_bounds__(256) void transpose_w(
    const float* __restrict__ W, ush* __restrict__ Wt, int ldW, int ldT)
{
    transpose_body(W, Wt, ldW, ldT);
}

struct TWArgs { const float* src[8]; ush* dst[8]; };
__global__ __launch_bounds__(256) void transpose_w8(TWArgs a, int ldW, int ldT)
{
    int g = blockIdx.z;
    transpose_body(a.src[g], a.dst[g], ldW, ldT);
}

// ---------------------------------------------------------------------------
// Embedding gather + f16 convert (unchanged)
// ---------------------------------------------------------------------------
__global__ __launch_bounds__(256) void gather_emb(
    const float* __restrict__ emb, const int* __restrict__ tok,
    ush* __restrict__ out, int tokld, int tmax)
{
    int i = blockIdx.x * 256 + threadIdx.x;
    int r = i >> 6, kq = (i & 63) * 8;
    int t = r >> 6, b = r & 63;
    ush v[8];
    if (t < tmax) {
        int tk = tok[b * tokld + t];
        const float* e = emb + (size_t)tk * EE + kq;
        #pragma unroll
        for (int j = 0; j < 8; j++) v[j] = f2h(e[j]);
    } else {
        #pragma unroll
        for (int j = 0; j < 8; j++) v[j] = 0;
    }
    *reinterpret_cast<f16x8*>(&out[(size_t)r * EE + kq]) =
        *reinterpret_cast<f16x8*>(v);
}

// ---------------------------------------------------------------------------
// f16 MFMA GEMM, 128x128 tile + XCD swizzle (proven; used for Gx/q/lin).
// MODE: 0 f32 C + bias; 2 f16 C; 3 f16 C tanh(acc+bias).
// ---------------------------------------------------------------------------
template <int MODE>
__global__ __launch_bounds__(256) void gemm_f16(
    const ush* __restrict__ A, int lda, const ush* __restrict__ Bt,
    const float* __restrict__ bias, void* __restrict__ Cv,
    int K, int Nld, int Mvalid)
{
    __shared__ ush As[128 * 64];
    __shared__ ush Bs[128 * 64];
    const int tid = threadIdx.x;
    const int lane = tid & 63;
    const int w = tid >> 6;
    const int wm = w >> 1, wn = w & 1;
    const int nwg = gridDim.x * gridDim.y;
    const int orig = blockIdx.y * gridDim.x + blockIdx.x;
    const int swz = (orig & 7) * (nwg >> 3) + (orig >> 3);
    const int m0 = (swz % gridDim.x) * 128;
    const int n0 = (swz / gridDim.x) * 128;

    f32x4 acc[4][4] = {};
    const int srow = w * 32 + (lane >> 3);
    const int skoff = (lane & 7) * 8;

    for (int kb = 0; kb < K; kb += 64) {
        #pragma unroll
        for (int c = 0; c < 4; c++) {
            const ush* ga = A + (size_t)(m0 + srow + c * 8) * lda + kb + skoff;
            gload16(ga, &As[(w * 4 + c) * 512]);
        }
        #pragma unroll
        for (int c = 0; c < 4; c++) {
            const ush* gb = Bt + (size_t)(n0 + srow + c * 8) * K + kb + skoff;
            gload16(gb, &Bs[(w * 4 + c) * 512]);
        }
        __syncthreads();

        #pragma unroll
        for (int kw = 0; kw < 2; kw++) {
            const int koff = kw * 32 + (lane >> 4) * 8;
            f16x8 af[4], bf[4];
            #pragma unroll
            for (int m = 0; m < 4; m++)
                af[m] = *(const f16x8*)&As[(wm * 64 + m * 16 + (lane & 15)) * 64 + koff];
            #pragma unroll
            for (int n = 0; n < 4; n++)
                bf[n] = *(const f16x8*)&Bs[(wn * 64 + n * 16 + (lane & 15)) * 64 + koff];
            #pragma unroll
            for (int m = 0; m < 4; m++)
                #pragma unroll
                for (int n = 0; n < 4; n++)
                    acc[m][n] = __builtin_amdgcn_mfma_f32_16x16x32_f16(
                        af[m], bf[n], acc[m][n], 0, 0, 0);
        }
        __syncthreads();
    }

    #pragma unroll
    for (int n = 0; n < 4; n++) {
        int v = n0 + wn * 64 + n * 16 + (lane & 15);
        float bs = (MODE == 2) ? 0.f : (bias ? bias[v] : 0.f);
        #pragma unroll
        for (int m = 0; m < 4; m++) {
            int rbase = m0 + wm * 64 + m * 16 + (lane >> 4) * 4;
            #pragma unroll
            for (int r = 0; r < 4; r++) {
                int row = rbase + r;
                float val = acc[m][n][r] + bs;
                if (MODE == 0) {
                    if (row < Mvalid) ((float*)Cv)[(size_t)row * Nld + v] = val;
                } else if (MODE == 2) {
                    if (row < Mvalid) ((ush*)Cv)[(size_t)row * Nld + v] = f2h(val);
                } else {
                    if (row < Mvalid)
                        ((ush*)Cv)[(size_t)row * Nld + v] = f2h(tanhf(val));
                }
            }
        }
    }
}

// ===========================================================================
// Out-projection GEMM: 256x256 tile, BK=64, 8 waves (512 thr), LDS 128 KiB
// double-buffered, counted vmcnt(8) (T3+T4), 16B-slot XOR swizzle (T2,
// rule 21: inverse-swizzled GLOBAL source + swizzled ds_read; LDS dest
// linear). Raw s_barrier + manual waitcnt (never __syncthreads — it drains
// vmcnt). Protocol per step s:
//   B1: vmcnt(8) [tail: 0]; s_barrier   -> buf[s&1] staged (issued at s-2)
//   4 quadrants: ds_read frags (swz) ; lgkmcnt(0); 16 MFMA
//   B2: s_barrier                        -> all waves' reads of buf[s&1] done
//   stage step s+2 -> buf[s&1]           (lands by B1 of s+2)
// Accumulation order per output element identical to gemm_f16 (16 steps x
// ks 0,1) -> bit-identical results.
// ===========================================================================
__device__ __forceinline__ void stage256(
    const ush* __restrict__ A, const ush* __restrict__ Bt,
    int m0, int n0, int kb, ush* lbase, int w, int lane)
{
    #pragma unroll
    for (int j = 0; j < 4; j++) {
        int row = j * 64 + w * 8 + (lane >> 3);
        int c16 = (lane & 7) ^ (row & 7);
        gload16(A + (size_t)(m0 + row) * 1024 + kb + c16 * 8,
                lbase + j * 4096 + w * 512);
    }
    #pragma unroll
    for (int j = 0; j < 4; j++) {
        int row = j * 64 + w * 8 + (lane >> 3);
        int c16 = (lane & 7) ^ (row & 7);
        gload16(Bt + (size_t)(n0 + row) * 1024 + kb + c16 * 8,
                lbase + 16384 + j * 4096 + w * 512);
    }
}

__global__ __launch_bounds__(512) void gemm256_out(
    const ush* __restrict__ A,    // preh [3072][1024] f16 (pad rows masked)
    const ush* __restrict__ Bt,   // Wt [32000][1024] f16
    const float* __restrict__ bias, float* __restrict__ C)
{
    __shared__ ush lds[65536];    // 128 KiB: buf b at b*32768 (A 16384 | B 16384)
    const int tid = threadIdx.x;
    const int lane = tid & 63;
    const int w = tid >> 6;            // wave 0..7
    const int wm = w >> 2, wn = w & 3; // 2x4 wave grid; wave tile 128x64
    // bijective XCD swizzle (nwg = 1500, 1500 % 8 != 0 -> m204 formula)
    const int orig = blockIdx.x;
    const int xcd = orig & 7, ii = orig >> 3;
    const int swz = (xcd < 4 ? xcd * 188 : 752 + (xcd - 4) * 187) + ii;
    const int m0 = (swz % 12) * 256;
    const int n0 = (swz / 12) * 256;

    f32x4 acc[8][4] = {};

    // prologue: step 0 -> buf0, step 1 -> buf1 (16 loads in flight)
    stage256(A, Bt, m0, n0, 0,  lds,         w, lane);
    stage256(A, Bt, m0, n0, 64, lds + 32768, w, lane);

    for (int s = 0; s < 16; s++) {
        if (s < 14) { asm volatile("s_waitcnt vmcnt(8)" ::: "memory"); }
        else        { asm volatile("s_waitcnt vmcnt(0)" ::: "memory"); }
        __builtin_amdgcn_sched_barrier(0);
        __builtin_amdgcn_s_barrier();
        __builtin_amdgcn_sched_barrier(0);

        const ush* Ab = lds + (s & 1) * 32768;
        const ush* Bb = Ab + 16384;
        f16x8 bf[4][2];
        #pragma unroll
        for (int q = 0; q < 4; q++) {
            f16x8 af[2][2];
            #pragma unroll
            for (int m2 = 0; m2 < 2; m2++)
                #pragma unroll
                for (int ks = 0; ks < 2; ks++) {
                    int row = wm * 128 + (q * 2 + m2) * 16 + (lane & 15);
                    int slot = ks * 4 + (lane >> 4);
                    af[m2][ks] = *(const f16x8*)&Ab[row * 64 + (slot ^ (row & 7)) * 8];
                }
            if (q == 0) {
                #pragma unroll
                for (int nn = 0; nn < 4; nn++)
                    #pragma unroll
                    for (int ks = 0; ks < 2; ks++) {
                        int row = wn * 64 + nn * 16 + (lane & 15);
                        int slot = ks * 4 + (lane >> 4);
                        bf[nn][ks] = *(const f16x8*)&Bb[row * 64 + (slot ^ (row & 7)) * 8];
                    }
            }
            asm volatile("s_waitcnt lgkmcnt(0)" ::: "memory");
            __builtin_amdgcn_sched_barrier(0);
            #pragma unroll
            for (int m2 = 0; m2 < 2; m2++)
                #pragma unroll
                for (int nn = 0; nn < 4; nn++)
                    #pragma unroll
                    for (int ks = 0; ks < 2; ks++)
                        acc[q * 2 + m2][nn] = __builtin_amdgcn_mfma_f32_16x16x32_f16(
                            af[m2][ks], bf[nn][ks], acc[q * 2 + m2][nn], 0, 0, 0);
        }
        __builtin_amdgcn_sched_barrier(0);
        __builtin_amdgcn_s_barrier();    // all waves done reading buf[s&1]
        __builtin_amdgcn_sched_barrier(0);
        if (s + 2 < 16)
            stage256(A, Bt, m0, n0, (s + 2) * 64, lds + (s & 1) * 32768, w, lane);
    }

    // epilogue: out[b][s][v] permute + bias, guard row<3008
    #pragma unroll
    for (int nn = 0; nn < 4; nn++) {
        int v = n0 + wn * 64 + nn * 16 + (lane & 15);
        float bs = bias[v];
        #pragma unroll
        for (int mm = 0; mm < 8; mm++) {
            int rbase = m0 + wm * 128 + mm * 16 + (lane >> 4) * 4;
            #pragma unroll
            for (int r = 0; r < 4; r++) {
                int row = rbase + r;
                if (row < 3008) {
                    int b = row & 63, ss = row >> 6;
                    C[((size_t)b * NSS + ss) * VV + v] = acc[mm][nn][r] + bs;
                }
            }
        }
    }
}

// ===========================================================================
// Persistent recurrent kernel (round-9 proven, untouched).
// ===========================================================================
struct RecArgs {
    const ush *Whe, *Whd, *Gxe, *Gxd;
    const float *ebi, *ebf, *ebo, *ebc;
    const float *dbi, *dbf, *dbo, *dbc;
    ush *enc16, *Hcat;
    unsigned* bar;
};

__device__ __forceinline__ void stageWh(const ush* __restrict__ Wh, int j, int kb,
                                        int w, int lane, ush* Ws)
{
    #pragma unroll
    for (int c8 = 0; c8 < 4; c8++) {
        int s = (c8 * 4 + w) * 64 + lane;
        int r = s >> 4, scc = (s & 15) ^ (r & 7);
        gload16(Wh + ((size_t)((r >> 4) * 1024 + j * 16 + (r & 15))) * 1024 + kb + scc * 8,
                Ws + (size_t)(c8 * 4 + w) * 512);
    }
}

__device__ __forceinline__ void lstm_step2(
    const ush* __restrict__ hsrc, int hstride, ush* __restrict__ hdst, int dstride,
    const ush* __restrict__ gx,
    float Bi, float Bf, float Bo, float Bc, float& creg,
    ush (*Whs)[8192], ush (*AsL)[2048],
    int rg, int j, int tid, unsigned* bar, unsigned target)
{
    const int w = tid >> 6, lane = tid & 63;
    const int r = tid >> 4, sl = tid & 15;
    const int gb = rg * 16 + r;
    const int gcc = j * 16 + sl;

    const ush* gxr = gx + (size_t)gb * 4096 + gcc;
    ush gxi = gxr[0], gxf = gxr[1024], gxo = gxr[2048], gxc = gxr[3072];

    if (hsrc) {
        uint4 ra[8];
        const ush* rowp = hsrc + (size_t)gb * hstride;
        #pragma unroll
        for (int ch = 0; ch < 8; ch++)
            ra[ch] = *reinterpret_cast<const uint4*>(rowp + ch * 128 + sl * 8);
        #pragma unroll
        for (int ch = 0; ch < 8; ch++)
            *reinterpret_cast<uint4*>(&AsL[ch][r * 128 + (sl ^ (r & 7)) * 8]) = ra[ch];
    } else {
        uint4 z = {0, 0, 0, 0};
        #pragma unroll
        for (int ch = 0; ch < 8; ch++)
            *reinterpret_cast<uint4*>(&AsL[ch][r * 128 + sl * 8]) = z;
    }
    __syncthreads();

    f32x4 acc = {};
    #pragma unroll
    for (int ch = 0; ch < 8; ch++) {
        #pragma unroll
        for (int kw = 0; kw < 4; kw++) {
            int colo = kw * 32 + (lane >> 4) * 8;
            int ar = lane & 15;
            f16x8 af = *(const f16x8*)&AsL[ch][(ar * 128 + colo) ^ ((ar & 7) << 3)];
            int br = w * 16 + (lane & 15);
            f16x8 bfv = *(const f16x8*)&Whs[ch][(br * 128 + colo) ^ ((br & 7) << 3)];
            acc = __builtin_amdgcn_mfma_f32_16x16x32_f16(af, bfv, acc, 0, 0, 0);
        }
    }
    __syncthreads();
    float* zb = (float*)AsL;
    #pragma unroll
    for (int rr = 0; rr < 4; rr++)
        zb[(w * 16 + (lane >> 4) * 4 + rr) * 16 + (lane & 15)] = acc[rr];
    __syncthreads();

    float zi = zb[(r) * 16 + sl]      + Bi + h2f(gxi);
    float zf = zb[(16 + r) * 16 + sl] + Bf + h2f(gxf);
    float zo = zb[(32 + r) * 16 + sl] + Bo + h2f(gxo);
    float zc = zb[(48 + r) * 16 + sl] + Bc + h2f(gxc);
    float F = sigm(zf), I = sigm(zi), O = sigm(zo), G = tanhf(zc);
    creg = F * creg + I * G;
    float hn = O * tanhf(creg);
    unsigned hv = (unsigned)f2h(hn);
    unsigned other = __shfl_xor(hv, 1, 64);
    if ((lane & 1) == 0)
        st_agent_u32(hdst + (size_t)gb * dstride + gcc, hv | (other << 16));

    gbar(bar, target);
}

__global__ __launch_bounds__(256) void recurrent_all(RecArgs a)
{
    __shared__ ush Whs[8][8192];
    __shared__ ush AsL[8][2048];
    const int bid = blockIdx.x;
    const int rg = bid >> 6;
    const int j = bid & 63;
    const int tid = threadIdx.x;
    const int w = tid >> 6, lane = tid & 63;
    const int gcc = j * 16 + (tid & 15);
    unsigned* bar = a.bar + rg * 64;
    unsigned nb = 0;
    float creg = 0.f;

    for (int ch = 0; ch < 8; ch++) stageWh(a.Whe, j, ch * 128, w, lane, Whs[ch]);
    {
        float Bi = a.ebi[gcc], Bf = a.ebf[gcc], Bo = a.ebo[gcc], Bc = a.ebc[gcc];
        for (int t = 0; t < TXX; t++) {
            const ush* hsrc = (t == 0) ? nullptr : a.enc16 + (size_t)(t - 1) * 65536;
            lstm_step2(hsrc, 1024, a.enc16 + (size_t)t * 65536, 1024,
                       a.Gxe + (size_t)t * 262144, Bi, Bf, Bo, Bc, creg,
                       Whs, AsL, rg, j, tid, bar, ++nb * 64u);
        }
    }
    for (int ch = 0; ch < 8; ch++) stageWh(a.Whd, j, ch * 128, w, lane, Whs[ch]);
    {
        float Bi = a.dbi[gcc], Bf = a.dbf[gcc], Bo = a.dbo[gcc], Bc = a.dbc[gcc];
        for (int s = 0; s < NSS; s++) {
            const ush* hsrc = (s == 0) ? a.enc16 + (size_t)127 * 65536
                                       : a.Hcat + (size_t)(s - 1) * 64 * 2048;
            int hstride = (s == 0) ? 1024 : 2048;
            lstm_step2(hsrc, hstride, a.Hcat + (size_t)s * 64 * 2048, 2048,
                       a.Gxd + (size_t)s * 262144, Bi, Bf, Bo, Bc, creg,
                       Whs, AsL, rg, j, tid, bar, ++nb * 64u);
        }
    }
}

// ---------------------------------------------------------------------------
// Batched attention (round-10 proven): one block per (s, b).
// ---------------------------------------------------------------------------
__global__ __launch_bounds__(256) void attn_batched(
    const float* __restrict__ q, const ush* __restrict__ enc16,
    ush* __restrict__ Hcat)
{
    int s = blockIdx.x, b = blockIdx.y;
    int row = s * 64 + b;
    int tid = threadIdx.x;
    __shared__ float qs[1024];
    __shared__ float sc[130];

    for (int i = tid; i < 1024; i += 256) qs[i] = q[(size_t)row * 1024 + i];
    __syncthreads();

    int wave = tid >> 6, lane = tid & 63;
    for (int i = 0; i < 32; i++) {
        int t = wave * 32 + i;
        const ush* e = enc16 + ((size_t)t * 64 + b) * 1024;
        float sv = 0.f;
        #pragma unroll
        for (int jj = 0; jj < 16; jj++) sv += qs[lane + jj * 64] * h2f(e[lane + jj * 64]);
        #pragma unroll
        for (int o = 32; o > 0; o >>= 1) sv += __shfl_down(sv, o, 64);
        if (lane == 0) sc[t] = sv;
    }
    __syncthreads();

    if (wave == 0) {
        float v = fmaxf(sc[lane], sc[lane + 64]);
        #pragma unroll
        for (int o = 32; o > 0; o >>= 1) v = fmaxf(v, __shfl_down(v, o, 64));
        if (lane == 0) sc[128] = v;
    }
    __syncthreads();
    float mx = sc[128];
    if (wave == 0) {
        float e0 = expf(sc[lane] - mx), e1 = expf(sc[lane + 64] - mx);
        sc[lane] = e0; sc[lane + 64] = e1;
        float v = e0 + e1;
        #pragma unroll
        for (int o = 32; o > 0; o >>= 1) v += __shfl_down(v, o, 64);
        if (lane == 0) sc[129] = v;
    }
    __syncthreads();
    float inv = 1.f / sc[129];

    int h0 = tid * 4;
    float a0 = 0.f, a1 = 0.f, a2 = 0.f, a3 = 0.f;
    #pragma unroll 4
    for (int t = 0; t < 128; t++) {
        float av = sc[t] * inv;
        ushx4 ev = *reinterpret_cast<const ushx4*>(
            enc16 + ((size_t)t * 64 + b) * 1024 + h0);
        a0 += av * h2f(ev[0]); a1 += av * h2f(ev[1]);
        a2 += av * h2f(ev[2]); a3 += av * h2f(ev[3]);
    }
    ushx4 o = {f2h(a0), f2h(a1), f2h(a2), f2h(a3)};
    *reinterpret_cast<ushx4*>(&Hcat[(size_t)row * 2048 + 1024 + h0]) = o;
}

// ---------------------------------------------------------------------------
extern "C" void kernel_launch(void* const* d_in, const int* in_sizes, int n_in,
                              void* d_out, int out_size, void* d_ws, size_t ws_size,
                              hipStream_t stream)
{
    const int*   x       = (const int*)d_in[0];
    const int*   y       = (const int*)d_in[1];
    const float* enc_emb = (const float*)d_in[2];
    const float* dec_emb = (const float*)d_in[3];
    const float* encW[4] = {(const float*)d_in[4], (const float*)d_in[6],
                            (const float*)d_in[8], (const float*)d_in[10]};
    const float* encB[4] = {(const float*)d_in[5], (const float*)d_in[7],
                            (const float*)d_in[9], (const float*)d_in[11]};
    const float* decW[4] = {(const float*)d_in[12], (const float*)d_in[14],
                            (const float*)d_in[16], (const float*)d_in[18]};
    const float* decB[4] = {(const float*)d_in[13], (const float*)d_in[15],
                            (const float*)d_in[17], (const float*)d_in[19]};
    const float* attn_w  = (const float*)d_in[20];
    const float* attn_b  = (const float*)d_in[21];
    const float* lin_w   = (const float*)d_in[22];
    const float* lin_b   = (const float*)d_in[23];
    const float* out_w   = (const float*)d_in[24];
    const float* out_b   = (const float*)d_in[25];

    // ws layout: proven extents (high-water 30408704 f)
    float* ws = (float*)d_ws;
    ush*   preh   = (ush*)(ws + 393216);         // 3072x1024 ush (3008 valid)
    ush*   enc16  = (ush*)(ws + 1966080);        // 128x64x1024 ush
    ush*   Wt     = (ush*)(ws + 6160384);        // 32000x1024 ush
    ush*   Whe    = (ush*)(ws + 22544384);       // 4096x1024 ush
    ush*   Whd    = (ush*)(ws + 24641536);
    ush*   Wxe    = (ush*)(ws + 26738688);       // 4096x512 ush
    ush*   Wxd    = (ush*)(ws + 27787264);
    ush*   attn_t = (ush*)(ws + 28835840);       // 1024x1024 ush
    ush*   lin_t  = (ush*)(ws + 29360128);       // 1024x2048 ush
    unsigned* bar = (unsigned*)(preh + (size_t)3008 * 1024);  // pad rows

    // dead-before-outproj scratch in d_out
    ush*   Gx_enc = (ush*)d_out;                     // 8192*4096
    ush*   Gx_dec = Gx_enc + (size_t)8192 * 4096;    // 3072*4096
    ush*   Xe     = Gx_dec + (size_t)3072 * 4096;    // 8192*512
    ush*   Ye     = Xe + (size_t)8192 * 512;         // 3072*512
    ush*   Hcat   = Ye + (size_t)3072 * 512;         // 3072*2048
    float* qbuf   = (float*)(Hcat + (size_t)3072 * 2048);  // 3072*1024 f32

    hipMemsetAsync(preh, 0, (size_t)3072 * 1024 * 2, stream); // pad + counters

    // ---- weight prep (5 launches) ----
    transpose_w<<<dim3(VV / 32, 32), 256, 0, stream>>>(out_w, Wt, VV, HH);
    transpose_w<<<dim3(32, 32), 256, 0, stream>>>(attn_w, attn_t, HH, HH);
    transpose_w<<<dim3(32, 64), 256, 0, stream>>>(lin_w, lin_t, HH, 2048);
    {
        TWArgs wh, wx;
        for (int g = 0; g < 4; g++) {
            wh.src[g]     = encW[g] + (size_t)EE * HH;
            wh.dst[g]     = Whe + (size_t)g * 1024 * 1024;
            wh.src[4 + g] = decW[g] + (size_t)EE * HH;
            wh.dst[4 + g] = Whd + (size_t)g * 1024 * 1024;
            wx.src[g]     = encW[g];
            wx.dst[g]     = Wxe + (size_t)g * 1024 * 512;
            wx.src[4 + g] = decW[g];
            wx.dst[4 + g] = Wxd + (size_t)g * 1024 * 512;
        }
        transpose_w8<<<dim3(32, 32, 8), 256, 0, stream>>>(wh, HH, HH);
        transpose_w8<<<dim3(32, 16, 8), 256, 0, stream>>>(wx, HH, EE);
    }

    // ---- embedding gathers ----
    gather_emb<<<dim3(2048), 256, 0, stream>>>(enc_emb, x, Xe, TXX, TXX);
    gather_emb<<<dim3(768), 256, 0, stream>>>(dec_emb, y, Ye, TYY, NSS);

    // ---- x-side gate precompute ----
    gemm_f16<2><<<dim3(64, 32), 256, 0, stream>>>(
        Xe, EE, Wxe, nullptr, Gx_enc, EE, 4096, 8192);
    gemm_f16<2><<<dim3(24, 32), 256, 0, stream>>>(
        Ye, EE, Wxd, nullptr, Gx_dec, EE, 4096, 3072);

    // ---- persistent recurrent kernel (proven; untouched) ----
    RecArgs ra;
    ra.Whe = Whe; ra.Whd = Whd; ra.Gxe = Gx_enc; ra.Gxd = Gx_dec;
    ra.ebi = encB[0]; ra.ebf = encB[1]; ra.ebo = encB[2]; ra.ebc = encB[3];
    ra.dbi = decB[0]; ra.dbf = decB[1]; ra.dbo = decB[2]; ra.dbc = decB[3];
    ra.enc16 = enc16; ra.Hcat = Hcat; ra.bar = bar;
    recurrent_all<<<dim3(256), dim3(256), 0, stream>>>(ra);

    // ---- post-recurrent batched phases ----
    gemm_f16<0><<<dim3(24, 8), 256, 0, stream>>>(
        Hcat, 2048, attn_t, attn_b, qbuf, HH, HH, 3008);
    attn_batched<<<dim3(NSS, 64), 256, 0, stream>>>(qbuf, enc16, Hcat);
    gemm_f16<3><<<dim3(24, 8), 256, 0, stream>>>(
        Hcat, 2048, lin_t, lin_b, preh, 2048, HH, 3008);

    // ---- output projection: 256^2 8-wave counted-vmcnt kernel ----
    gemm256_out<<<dim3(1500), dim3(512), 0, stream>>>(
        preh, Wt, out_b, (float*)d_out);
}